// Round 10
// baseline (162.706 us; speedup 1.0000x reference)
//
#include <hip/hip_runtime.h>
#include <stdint.h>

typedef __attribute__((ext_vector_type(8))) short shortx8;
typedef __attribute__((ext_vector_type(4))) float floatx4;

static constexpr int SEQ_    = 2048;
static constexpr int DMODEL  = 1024;
static constexpr int HDIM    = 64;
static constexpr int BATCH_  = 2;
static constexpr int NHEADS  = 16;
static constexpr int WINDOW_ = 64;
static constexpr int GTOK    = 4;
static constexpr int RTOK    = 32;
static constexpr int ROWS    = BATCH_ * SEQ_;   // 4096
static constexpr int QKVN    = 3 * DMODEL;      // 3072

__device__ inline unsigned short f2bf(float f) {
  union { float f; unsigned int u; } x; x.f = f;
  unsigned int r = (x.u + 0x7FFFu + ((x.u >> 16) & 1u)) >> 16;
  return (unsigned short)r;
}
__device__ inline float bf2f(unsigned short b) {
  union { unsigned int u; float f; } x; x.u = ((unsigned int)b) << 16;
  return x.f;
}

__device__ inline void gload_lds16(const void* g, void* l) {
  __builtin_amdgcn_global_load_lds(
      (const __attribute__((address_space(1))) void*)g,
      (__attribute__((address_space(3))) void*)l, 16, 0, 0);
}

// ---- MFMA GEMM core: 128x64 tile, K=1024, BK=64, dbuf + COUNTED vmcnt (T4).
// Used by k2. Per K-step: STAGE(next) -> vmcnt(6) -> barrier -> COMPUTE -> barrier.
__device__ __forceinline__ void gemm_bk64_128x64(
    const unsigned short* __restrict__ aP0, const unsigned short* __restrict__ aP1,
    const unsigned short* __restrict__ aP2, const unsigned short* __restrict__ aP3,
    const unsigned short* __restrict__ bP0, const unsigned short* __restrict__ bP1,
    unsigned short* smem, const int wave, const int lane, floatx4 (&acc)[4][2]) {
  const int quad = lane >> 4, l16 = lane & 15;
  const int wm = (wave >> 1) * 64, wn = (wave & 1) * 32;
  const int h = l16 & 7;
  auto STAGE = [&](int c, int k0) {
    unsigned short* Ad = smem + c * 12288 + wave * 2048;          // 32 rows x 64
    unsigned short* Bd = smem + c * 12288 + 8192 + wave * 1024;   // 16 rows x 64
    gload_lds16(aP0 + k0, Ad);
    gload_lds16(aP1 + k0, Ad + 512);
    gload_lds16(aP2 + k0, Ad + 1024);
    gload_lds16(aP3 + k0, Ad + 1536);
    gload_lds16(bP0 + k0, Bd);
    gload_lds16(bP1 + k0, Bd + 512);
  };
  auto COMPUTE = [&](int c) {
    const unsigned short* A = smem + c * 12288;
    const unsigned short* B = A + 8192;
    #pragma unroll
    for (int kk = 0; kk < 2; kk++) {
      shortx8 af[4], bfr[2];
      #pragma unroll
      for (int s = 0; s < 4; s++)
        af[s] = *(const shortx8*)&A[(wm + s * 16 + l16) * 64 + (((quad + kk * 4) ^ h) * 8)];
      #pragma unroll
      for (int s = 0; s < 2; s++)
        bfr[s] = *(const shortx8*)&B[(wn + s * 16 + l16) * 64 + (((quad + kk * 4) ^ h) * 8)];
      #pragma unroll
      for (int sm = 0; sm < 4; sm++)
        #pragma unroll
        for (int sn = 0; sn < 2; sn++)
          acc[sm][sn] = __builtin_amdgcn_mfma_f32_16x16x32_bf16(af[sm], bfr[sn], acc[sm][sn], 0, 0, 0);
    }
  };
  STAGE(0, 0);
  int cur = 0;
  #pragma unroll 1
  for (int t = 0; t < 15; ++t) {
    STAGE(cur ^ 1, (t + 1) * 64);              // prefetch next tile (6 loads in flight)
    asm volatile("s_waitcnt vmcnt(6)" ::: "memory");   // prev tile's 6 loads landed
    __builtin_amdgcn_s_barrier();
    __builtin_amdgcn_sched_barrier(0);
    COMPUTE(cur);
    __builtin_amdgcn_sched_barrier(0);
    __builtin_amdgcn_s_barrier();
    cur ^= 1;
  }
  asm volatile("s_waitcnt vmcnt(0)" ::: "memory");
  __builtin_amdgcn_s_barrier();
  __builtin_amdgcn_sched_barrier(0);
  COMPUTE(cur);
}

// ---- MFMA GEMM core: 128x128 tile, K=1024, BK=64, dbuf + COUNTED vmcnt (T4).
// Used by k4. 64 KB LDS -> 2 blocks/CU. 32 MFMA per K-step per wave (4x4 frags),
// 8 staged loads/wave/step; vmcnt(8) keeps next tile's loads in flight across
// the barrier (geometry identical to the r2-refchecked 128x128 core).
__device__ __forceinline__ void gemm_bk64_128x128(
    const unsigned short* __restrict__ aP0, const unsigned short* __restrict__ aP1,
    const unsigned short* __restrict__ aP2, const unsigned short* __restrict__ aP3,
    const unsigned short* __restrict__ bP0, const unsigned short* __restrict__ bP1,
    const unsigned short* __restrict__ bP2, const unsigned short* __restrict__ bP3,
    unsigned short* smem, const int wave, const int lane, floatx4 (&acc)[4][4]) {
  const int quad = lane >> 4, l16 = lane & 15;
  const int wm = (wave >> 1) * 64, wn = (wave & 1) * 64;
  const int h = l16 & 7;
  auto STAGE = [&](int c, int k0) {
    unsigned short* Ad = smem + c * 16384 + wave * 2048;          // 32 rows x 64
    unsigned short* Bd = smem + c * 16384 + 8192 + wave * 2048;   // 32 rows x 64
    gload_lds16(aP0 + k0, Ad);
    gload_lds16(aP1 + k0, Ad + 512);
    gload_lds16(aP2 + k0, Ad + 1024);
    gload_lds16(aP3 + k0, Ad + 1536);
    gload_lds16(bP0 + k0, Bd);
    gload_lds16(bP1 + k0, Bd + 512);
    gload_lds16(bP2 + k0, Bd + 1024);
    gload_lds16(bP3 + k0, Bd + 1536);
  };
  auto COMPUTE = [&](int c) {
    const unsigned short* A = smem + c * 16384;
    const unsigned short* B = A + 8192;
    #pragma unroll
    for (int kk = 0; kk < 2; kk++) {
      shortx8 af[4], bfr[4];
      #pragma unroll
      for (int s = 0; s < 4; s++)
        af[s] = *(const shortx8*)&A[(wm + s * 16 + l16) * 64 + (((quad + kk * 4) ^ h) * 8)];
      #pragma unroll
      for (int s = 0; s < 4; s++)
        bfr[s] = *(const shortx8*)&B[(wn + s * 16 + l16) * 64 + (((quad + kk * 4) ^ h) * 8)];
      #pragma unroll
      for (int sm = 0; sm < 4; sm++)
        #pragma unroll
        for (int sn = 0; sn < 4; sn++)
          acc[sm][sn] = __builtin_amdgcn_mfma_f32_16x16x32_bf16(af[sm], bfr[sn], acc[sm][sn], 0, 0, 0);
    }
  };
  STAGE(0, 0);
  int cur = 0;
  #pragma unroll 1
  for (int t = 0; t < 15; ++t) {
    STAGE(cur ^ 1, (t + 1) * 64);              // prefetch next tile (8 loads in flight)
    asm volatile("s_waitcnt vmcnt(8)" ::: "memory");   // prev tile's 8 loads landed
    __builtin_amdgcn_s_barrier();
    __builtin_amdgcn_sched_barrier(0);
    COMPUTE(cur);
    __builtin_amdgcn_sched_barrier(0);
    __builtin_amdgcn_s_barrier();
    cur ^= 1;
  }
  asm volatile("s_waitcnt vmcnt(0)" ::: "memory");
  __builtin_amdgcn_s_barrier();
  __builtin_amdgcn_sched_barrier(0);
  COMPUTE(cur);
}

// =================== K1: LN + weight converts + mask/tier lists ===================
// Compressed grid (4608): [0,1536) wqT 64k x 32n strips; [1536,2560) LN 1 row/wave;
// [2560,3072) woT 64k x 32n strips; [3072,3584) Wvs 32k x 64v uint stores;
// [3584,4608) mask/tier lists, 2 rows/block.
__global__ __launch_bounds__(256) void k1_prep(
    const float* __restrict__ x, const float* __restrict__ w_qkv,
    const float* __restrict__ w_out, const float* __restrict__ gamma,
    const float* __restrict__ beta, const int* __restrict__ ridx,
    unsigned short* __restrict__ xn, unsigned short* __restrict__ wqT,
    unsigned short* __restrict__ woT, unsigned short* __restrict__ Wvs,
    int* __restrict__ cols, int* __restrict__ cnt, int* __restrict__ tmx,
    int* __restrict__ cnts2, int* __restrict__ qlist) {
  __shared__ float tile[64][33];
  __shared__ int rl2[2][RTOK];
  __shared__ int scw2[2], scnw2[2], stm2[2];
  const int bx = blockIdx.x;
  const int t = threadIdx.x;
  if (bx < 1536) {
    // wqT: (K=1024 x N=3072) -> (N x K) bf16; strip = 64 k x 32 n
    const int n0 = (bx % 96) * 32, k0 = (bx / 96) * 64;
    const int tx = t & 31, ty = t >> 5;
    #pragma unroll
    for (int r = ty; r < 64; r += 8)
      tile[r][tx] = w_qkv[(size_t)(k0 + r) * QKVN + n0 + tx];
    __syncthreads();
    // stores: 32 lanes cover 64 k as uint pairs -> 128B contiguous segments
    #pragma unroll
    for (int r = ty; r < 32; r += 8) {
      unsigned int lo = f2bf(tile[2 * tx][r]);
      unsigned int hi = f2bf(tile[2 * tx + 1][r]);
      *(unsigned int*)&wqT[(size_t)(n0 + r) * DMODEL + k0 + 2 * tx] = lo | (hi << 16);
    }
  } else if (bx < 2560) {
    // LN: one row per wave (wave-local shfl reduction, no barriers)
    const int wave = t >> 6, lane = t & 63;
    const int row = (bx - 1536) * 4 + wave;
    const float4* xr = (const float4*)(x + (size_t)row * DMODEL);
    float4 v[4];
    #pragma unroll
    for (int j = 0; j < 4; j++) v[j] = xr[lane + j * 64];
    float s = 0.f;
    #pragma unroll
    for (int j = 0; j < 4; j++) s += v[j].x + v[j].y + v[j].z + v[j].w;
    #pragma unroll
    for (int o = 32; o > 0; o >>= 1) s += __shfl_xor(s, o);
    const float mean = s * (1.0f / DMODEL);
    float q = 0.f;
    #pragma unroll
    for (int j = 0; j < 4; j++) {
      float a = v[j].x - mean, b = v[j].y - mean, c = v[j].z - mean, d = v[j].w - mean;
      q += a * a + b * b + c * c + d * d;
    }
    #pragma unroll
    for (int o = 32; o > 0; o >>= 1) q += __shfl_xor(q, o);
    const float rs = rsqrtf(q * (1.0f / DMODEL) + 1e-5f);
    ushort4* xo = (ushort4*)(xn + (size_t)row * DMODEL);
    #pragma unroll
    for (int j = 0; j < 4; j++) {
      float4 g = ((const float4*)gamma)[lane + j * 64];
      float4 bb = ((const float4*)beta)[lane + j * 64];
      ushort4 ov;
      ov.x = f2bf((v[j].x - mean) * rs * g.x + bb.x);
      ov.y = f2bf((v[j].y - mean) * rs * g.y + bb.y);
      ov.z = f2bf((v[j].z - mean) * rs * g.z + bb.z);
      ov.w = f2bf((v[j].w - mean) * rs * g.w + bb.w);
      xo[lane + j * 64] = ov;
    }
  } else if (bx < 3072) {
    // woT: (K=1024 x N=1024) -> (N x K); strip = 64 k x 32 n
    const int idx = bx - 2560;
    const int n0 = (idx & 31) * 32, k0 = (idx >> 5) * 64;
    const int tx = t & 31, ty = t >> 5;
    #pragma unroll
    for (int r = ty; r < 64; r += 8)
      tile[r][tx] = w_out[(size_t)(k0 + r) * DMODEL + n0 + tx];
    __syncthreads();
    #pragma unroll
    for (int r = ty; r < 32; r += 8) {
      unsigned int lo = f2bf(tile[2 * tx][r]);
      unsigned int hi = f2bf(tile[2 * tx + 1][r]);
      *(unsigned int*)&woT[(size_t)(n0 + r) * DMODEL + k0 + 2 * tx] = lo | (hi << 16);
    }
  } else if (bx < 3584) {
    // Wvs convert: 32k x 64v strips, float2 loads + paired-uint stores
    const int idx = bx - 3072;
    const int v0 = (idx & 15) * 64, k0 = (idx >> 4) * 32;
    const int tx = t & 31, ty = t >> 5;
    #pragma unroll
    for (int r = ty; r < 32; r += 8) {
      const float2 w = *(const float2*)&w_qkv[(size_t)(k0 + r) * QKVN + 2 * DMODEL + v0 + 2 * tx];
      unsigned int lo = f2bf(w.x);
      unsigned int hi = f2bf(w.y);
      *(unsigned int*)&Wvs[(size_t)(k0 + r) * DMODEL + v0 + 2 * tx] = lo | (hi << 16);
    }
  } else {
    // masks: 2 rows per block (half = t>>7, c = t&127; all barriers block-uniform)
    const int h = t >> 7, c = t & 127;
    const int i = (bx - 3584) * 2 + h;
    if (c < RTOK) rl2[h][c] = ridx[i * RTOK + c];
    if (c == 0) { scw2[h] = 0; scnw2[h] = 0; stm2[h] = 0; }
    __syncthreads();
    const int wstart = (i - WINDOW_ > 0) ? (i - WINDOW_) : 0;
    int j = -1;
    bool valid = false;
    bool iswin = (c < 65);
    if (c < 65) {                       // window candidates (incl diagonal)
      j = i - WINDOW_ + c;
      valid = (j >= 0);
    } else if (c < 73) {                // global cols outside window
      int g = c - 65;
      j = (g < 4) ? g : (SEQ_ - 8 + g);
      valid = (j <= i) && (j < wstart);
    } else if (c < 73 + RTOK) {         // random cols outside window/global, deduped
      int r = c - 73;
      j = rl2[h][r];
      bool dup = false;
      for (int r2 = 0; r2 < r; r2++) dup = dup || (rl2[h][r2] == j);
      valid = (j <= i) && (j < wstart) && !(j < GTOK || j >= SEQ_ - GTOK) && !dup;
    }
    int tier = -1;
    if (valid) {
      int loc = ((i - j) <= WINDOW_) ? 1 : 0;
      int glb = (j < GTOK || j >= SEQ_ - GTOK) ? 1 : 0;
      int rnd = 0;
      for (int r = 0; r < RTOK; r++) rnd |= (rl2[h][r] == j) ? 1 : 0;
      tier = loc + glb + rnd;
      atomicMax(&stm2[h], tier);
    }
    __syncthreads();
    const int tm = stm2[h];
    if (valid && tier == tm) {
      if (iswin) {
        int pos = atomicAdd(&scw2[h], 1);
        cols[i * 128 + pos] = j;
      } else {
        int pos = 127 - atomicAdd(&scnw2[h], 1);
        cols[i * 128 + pos] = j;
      }
    }
    __syncthreads();
    if (c == 0) {
      cnt[i] = scw2[h] + scnw2[h];
      tmx[i] = tm;
      cnts2[i] = scw2[h] | (scnw2[h] << 16);
      if (i < 68 || i >= SEQ_ - 4) {
        int cc = (i < 68) ? i : 68 + (i - (SEQ_ - 4));
        qlist[cc * 2 + 0] = (tm == 3) ? i : -1;
        qlist[cc * 2 + 1] = (tm == 3) ? (SEQ_ + i) : -1;
      }
    }
  }
}

// =================== K2: Wvo weight-GEMM + tier-3 q/k/v gather-GEMMs ===============
__global__ __launch_bounds__(256) void k2_wgemm(
    const unsigned short* __restrict__ woT, const unsigned short* __restrict__ Wvs,
    unsigned short* __restrict__ WvoT, const unsigned short* __restrict__ xn,
    const unsigned short* __restrict__ wqT, const int* __restrict__ qlist,
    unsigned short* __restrict__ qf, unsigned short* __restrict__ kf,
    unsigned short* __restrict__ vf) {
  __shared__ __align__(16) unsigned short smem[2 * 12288];   // 48 KB dbuf
  const int bx = blockIdx.x, t = threadIdx.x;
  const int wave = t >> 6, lane = t & 63;
  const int quad = lane >> 4, l16 = lane & 15;
  const int wm = (wave >> 1) * 64, wn = (wave & 1) * 32;
  const int r8 = lane >> 3;
  const int swo = ((lane & 7) ^ r8) * 8;     // inverse-swizzled source chunk
  floatx4 acc[4][2] = {};
  if (bx < 128) {
    const int bm = (bx >> 4) * 128, bn = (bx & 15) * 64;
    const unsigned short* a0 = woT + (size_t)(bm + wave * 32 + r8) * DMODEL + swo;
    const unsigned short* b0 = Wvs + (size_t)(bn + wave * 16 + r8) * DMODEL + swo;
    gemm_bk64_128x64(a0, a0 + 8 * DMODEL, a0 + 16 * DMODEL, a0 + 24 * DMODEL,
                     b0, b0 + 8 * DMODEL, smem, wave, lane, acc);
    #pragma unroll
    for (int sm = 0; sm < 4; sm++)
      #pragma unroll
      for (int sn = 0; sn < 2; sn++)
        #pragma unroll
        for (int r = 0; r < 4; r++) {
          int row = bm + wm + sm * 16 + quad * 4 + r;
          int col = bn + wn + sn * 16 + l16;
          WvoT[(size_t)row * DMODEL + col] = f2bf(acc[sm][sn][r]);
        }
  } else {
    const int idx = bx - 128;
    const int job = idx >> 4, bn = (idx & 15) * 64;
    const int wsel = (job < 2) ? 0 : ((job == 2) ? 1 : 2);
    const unsigned short* BT = wqT + (size_t)wsel * DMODEL * DMODEL;
    unsigned short* dstbuf = (job == 0) ? qf
                           : (job == 1) ? (qf + (size_t)128 * DMODEL)
                           : (job == 2) ? kf : vf;
    const unsigned short* aPg[4];
    #pragma unroll
    for (int g = 0; g < 4; g++) {
      int m = wave * 32 + g * 8 + r8;        // 0..127 within tile (per-lane row)
      int row;
      if (job < 2) {
        int s = job * 128 + m;
        int ql = (s < 144) ? qlist[s] : -1;
        row = (ql < 0) ? 0 : ql;
      } else {
        row = (m < 16) ? ((m >> 3) * SEQ_ + (((m & 7) < 4) ? (m & 7) : (SEQ_ - 8 + (m & 7)))) : 0;
      }
      aPg[g] = xn + (size_t)row * DMODEL + swo;
    }
    const unsigned short* b0 = BT + (size_t)(bn + wave * 16 + r8) * DMODEL + swo;
    gemm_bk64_128x64(aPg[0], aPg[1], aPg[2], aPg[3],
                     b0, b0 + 8 * DMODEL, smem, wave, lane, acc);
    #pragma unroll
    for (int sm = 0; sm < 4; sm++)
      #pragma unroll
      for (int sn = 0; sn < 2; sn++)
        #pragma unroll
        for (int r = 0; r < 4; r++) {
          int m = wm + sm * 16 + quad * 4 + r;
          int col = bn + wn + sn * 16 + l16;
          dstbuf[(size_t)m * DMODEL + col] = f2bf(acc[sm][sn][r]);
        }
  }
}

// =================== K3: tier-3 softmax (first) + sliding-window xbar ==============
__global__ __launch_bounds__(256) void k3_xbar(
    const unsigned short* __restrict__ xn, const int* __restrict__ cols,
    const int* __restrict__ cnt, const int* __restrict__ tmx,
    const int* __restrict__ cnts2, const int* __restrict__ qlist,
    const unsigned short* __restrict__ qf, const unsigned short* __restrict__ kf,
    const unsigned short* __restrict__ vf,
    unsigned short* __restrict__ xbar, unsigned short* __restrict__ vbar) {
  const int bx = blockIdx.x, t = threadIdx.x;
  const int wave = t >> 6, lane = t & 63;
  if (bx >= 36) {
    __shared__ unsigned short win[80][256];   // rows [i0-64, i0+15] x 256 dims
    const int xb = bx - 36;
    const int b = xb >> 9, rest = xb & 511;
    const int i0 = (rest >> 2) * 16, dimbase = (rest & 3) * 256;
    const size_t xnb = (size_t)(b * SEQ_) * DMODEL;
    const int lo = i0 - 64;
    const int r0 = i0 + wave * 4;
    // ---- preload metadata for this wave's 4 rows (coalesced, before chains) ----
    int tm_[4], cw_[4], cnw_[4], jr0_[4], jr1_[4];
    #pragma unroll
    for (int rr = 0; rr < 4; rr++) {
      const int i = r0 + rr;
      tm_[rr] = tmx[i];
      int c2 = cnts2[i];
      cw_[rr] = c2 & 0xffff; cnw_[rr] = c2 >> 16;
      jr0_[rr] = cols[i * 128 + lane];
      jr1_[rr] = cols[i * 128 + 64 + lane];
    }
    // ---- stage 80 window rows, int4/lane: 2 rows per wave-iter ----
    {
      const int l5 = lane & 31, rsub = lane >> 5;
      #pragma unroll 5
      for (int it = 0; it < 10; it++) {
        int r = it * 8 + wave * 2 + rsub;
        int gr = lo + r;
        if (gr >= 0)
          *(int4*)&win[r][l5 * 8] =
              *(const int4*)(xn + xnb + (size_t)gr * DMODEL + dimbase + l5 * 8);
      }
    }
    __syncthreads();
    const unsigned short* xnd = xn + xnb + dimbase + lane * 4;
    auto add4 = [](float4& s, ushort4 v) {
      s.x += bf2f(v.x); s.y += bf2f(v.y); s.z += bf2f(v.z); s.w += bf2f(v.w);
    };
    auto sub4 = [](float4& s, ushort4 v) {
      s.x -= bf2f(v.x); s.y -= bf2f(v.y); s.z -= bf2f(v.z); s.w -= bf2f(v.w);
    };
    // ---- init sliding window sum for row r0: rows [max(0,r0-64), r0] ----
    float4 ws = {0, 0, 0, 0};
    {
      float4 t1 = {0,0,0,0}, t2 = {0,0,0,0}, t3 = {0,0,0,0};
      const int jstart = (r0 - 64 > 0) ? (r0 - 64) : 0;
      const int cn = r0 - jstart + 1;
      const int base = jstart - lo;
      int c = 0;
      for (; c + 4 <= cn; c += 4) {
        ushort4 v0 = *(const ushort4*)&win[base + c][lane * 4];
        ushort4 v1 = *(const ushort4*)&win[base + c + 1][lane * 4];
        ushort4 v2 = *(const ushort4*)&win[base + c + 2][lane * 4];
        ushort4 v3 = *(const ushort4*)&win[base + c + 3][lane * 4];
        add4(ws, v0); add4(t1, v1); add4(t2, v2); add4(t3, v3);
      }
      for (; c < cn; c++) add4(ws, *(const ushort4*)&win[base + c][lane * 4]);
      ws.x += t1.x + t2.x + t3.x; ws.y += t1.y + t2.y + t3.y;
      ws.z += t1.z + t2.z + t3.z; ws.w += t1.w + t2.w + t3.w;
    }
    for (int rr = 0; rr < 4; rr++) {
      const int i = r0 + rr;
      if (rr > 0) {   // slide: add row i, drop row i-65
        add4(ws, *(const ushort4*)&win[i - lo][lane * 4]);
        int dj = i - 65;
        if (dj >= 0) sub4(ws, *(const ushort4*)&win[dj - lo][lane * 4]);
      }
      const int tm = tm_[rr];
      ushort4 o;
      if (tm == 3) {
        o.x = o.y = o.z = o.w = 0;
      } else {
        const int cw = cw_[rr], cnw = cnw_[rr];
        const int jr1 = jr1_[rr];
        float4 s;
        if (tm == 1) {
          // s = ws + gather of cnw non-window cols; branchless global, 8-deep ILP
          s = ws;
          float4 t1 = {0,0,0,0}, t2 = {0,0,0,0}, t3 = {0,0,0,0};
          const int bb = 64 - cnw;
          int c = 0;
          for (; c + 8 <= cnw; c += 8) {
            ushort4 v0 = *(const ushort4*)(xnd + (size_t)__shfl(jr1, bb + c)     * DMODEL);
            ushort4 v1 = *(const ushort4*)(xnd + (size_t)__shfl(jr1, bb + c + 1) * DMODEL);
            ushort4 v2 = *(const ushort4*)(xnd + (size_t)__shfl(jr1, bb + c + 2) * DMODEL);
            ushort4 v3 = *(const ushort4*)(xnd + (size_t)__shfl(jr1, bb + c + 3) * DMODEL);
            ushort4 v4 = *(const ushort4*)(xnd + (size_t)__shfl(jr1, bb + c + 4) * DMODEL);
            ushort4 v5 = *(const ushort4*)(xnd + (size_t)__shfl(jr1, bb + c + 5) * DMODEL);
            ushort4 v6 = *(const ushort4*)(xnd + (size_t)__shfl(jr1, bb + c + 6) * DMODEL);
            ushort4 v7 = *(const ushort4*)(xnd + (size_t)__shfl(jr1, bb + c + 7) * DMODEL);
            add4(s, v0); add4(t1, v1); add4(t2, v2); add4(t3, v3);
            add4(s, v4); add4(t1, v5); add4(t2, v6); add4(t3, v7);
          }
          if (c + 4 <= cnw) {
            ushort4 v0 = *(const ushort4*)(xnd + (size_t)__shfl(jr1, bb + c)     * DMODEL);
            ushort4 v1 = *(const ushort4*)(xnd + (size_t)__shfl(jr1, bb + c + 1) * DMODEL);
            ushort4 v2 = *(const ushort4*)(xnd + (size_t)__shfl(jr1, bb + c + 2) * DMODEL);
            ushort4 v3 = *(const ushort4*)(xnd + (size_t)__shfl(jr1, bb + c + 3) * DMODEL);
            add4(s, v0); add4(t1, v1); add4(t2, v2); add4(t3, v3);
            c += 4;
          }
          for (; c < cnw; c++)
            add4(s, *(const ushort4*)(xnd + (size_t)__shfl(jr1, bb + c) * DMODEL));
          s.x += t1.x + t2.x + t3.x; s.y += t1.y + t2.y + t3.y;
          s.z += t1.z + t2.z + t3.z; s.w += t1.w + t2.w + t3.w;
        } else {      // tm == 2: small n, branchless global gathers
          const int jr0 = jr0_[rr];
          s.x = s.y = s.z = s.w = 0.f;
          for (int c = 0; c < cw; c++) {
            int j = (c < 64) ? __shfl(jr0, c) : __shfl(jr1, c - 64);
            add4(s, *(const ushort4*)(xnd + (size_t)j * DMODEL));
          }
          const int bb = 64 - cnw;
          for (int c = 0; c < cnw; c++)
            add4(s, *(const ushort4*)(xnd + (size_t)__shfl(jr1, bb + c) * DMODEL));
        }
        const float inv = 1.0f / (float)(cw + cnw);
        o.x = f2bf(s.x * inv); o.y = f2bf(s.y * inv);
        o.z = f2bf(s.z * inv); o.w = f2bf(s.w * inv);
      }
      *(ushort4*)(xbar + (size_t)(b * SEQ_ + i) * DMODEL + dimbase + lane * 4) = o;
    }
  } else {
    const int s = bx * 4 + wave;                // slot in [0,144)
    const int dst = (s < 144) ? qlist[s] : -1;
    if (dst < 0) return;
    const int b = dst >> 11, i = dst & (SEQ_ - 1);
    const int n = cnt[i];                       // tier-3 cols all in lower segment
    int myk = 0;
    if (lane < n) {
      int kj = cols[i * 128 + lane];
      myk = b * 8 + ((kj < 4) ? kj : (kj - (SEQ_ - 8)));
    }
    for (int h = 0; h < NHEADS; h++) {
      float qd = bf2f(qf[(size_t)s * DMODEL + h * HDIM + lane]);
      float w[8];
      float m = -1e30f;
      for (int c = 0; c < n; c++) {
        int ks = __shfl(myk, c);
        float kd = bf2f(kf[(size_t)ks * DMODEL + h * HDIM + lane]);
        float p = qd * kd;
        #pragma unroll
        for (int o = 32; o > 0; o >>= 1) p += __shfl_xor(p, o);
        p *= 0.375f;                    // 3 * (q.k / 8)
        w[c] = p;
        m = fmaxf(m, p);
      }
      float denom = 0.f, acc = 0.f;
      for (int c = 0; c < n; c++) {
        int ks = __shfl(myk, c);
        float e = __expf(w[c] - m);
        denom += e;
        acc += e * bf2f(vf[(size_t)ks * DMODEL + h * HDIM + lane]);
      }
      vbar[(size_t)s * DMODEL + h * HDIM + lane] = f2bf(acc / denom);
    }
  }
}

// =================== K4: main fused GEMM (128x128) + tier-3 fixup GEMM =============
__global__ __launch_bounds__(256) void k4_final(
    const unsigned short* __restrict__ xbar, const unsigned short* __restrict__ WvoT,
    const unsigned short* __restrict__ vbar, const unsigned short* __restrict__ woT,
    const int* __restrict__ qlist, const int* __restrict__ tmx,
    const float* __restrict__ x, float* __restrict__ out) {
  __shared__ __align__(16) unsigned short smem[2 * 16384];   // 64 KB dbuf
  __shared__ int rowinf[128];
  const int bx = blockIdx.x, t = threadIdx.x;
  const int wave = t >> 6, lane = t & 63;
  const int quad = lane >> 4, l16 = lane & 15;
  const int wm = (wave >> 1) * 64, wn = (wave & 1) * 64;
  const int r8 = lane >> 3;
  const int swo = ((lane & 7) ^ r8) * 8;
  floatx4 acc[4][4] = {};
  if (bx < 256) {
    // bijective XCD swizzle (256 % 8 == 0): blocks on one XCD share A panels (T1)
    const int bs = (bx & 7) * 32 + (bx >> 3);
    const int bm = (bs >> 3) * 128, bn = (bs & 7) * 128;
    if (t < 128) rowinf[t] = tmx[(bm + t) & (SEQ_ - 1)];
    const unsigned short* a0 = xbar + (size_t)(bm + wave * 32 + r8) * DMODEL + swo;
    const unsigned short* b0 = WvoT + (size_t)(bn + wave * 32 + r8) * DMODEL + swo;
    gemm_bk64_128x128(a0, a0 + 8 * DMODEL, a0 + 16 * DMODEL, a0 + 24 * DMODEL,
                      b0, b0 + 8 * DMODEL, b0 + 16 * DMODEL, b0 + 24 * DMODEL,
                      smem, wave, lane, acc);
    #pragma unroll
    for (int sm = 0; sm < 4; sm++)
      #pragma unroll
      for (int sn = 0; sn < 4; sn++)
        #pragma unroll
        for (int r = 0; r < 4; r++) {
          int m = wm + sm * 16 + quad * 4 + r;
          if (rowinf[m] != 3) {
            int col = bn + wn + sn * 16 + l16;
            size_t off = (size_t)(bm + m) * DMODEL + col;
            out[off] = acc[sm][sn][r] + x[off];
          }
        }
  } else {
    const int idx = bx - 256;
    const int bm = (idx >> 3) * 128, bn = (idx & 7) * 128;
    if (t < 128) {
      int s = bm + t;
      rowinf[t] = (s < 144) ? qlist[s] : -1;
    }
    const unsigned short* a0 = vbar + (size_t)(bm + wave * 32 + r8) * DMODEL + swo;
    const unsigned short* b0 = woT + (size_t)(bn + wave * 32 + r8) * DMODEL + swo;
    gemm_bk64_128x128(a0, a0 + 8 * DMODEL, a0 + 16 * DMODEL, a0 + 24 * DMODEL,
                      b0, b0 + 8 * DMODEL, b0 + 16 * DMODEL, b0 + 24 * DMODEL,
                      smem, wave, lane, acc);
    #pragma unroll
    for (int sm = 0; sm < 4; sm++)
      #pragma unroll
      for (int sn = 0; sn < 4; sn++)
        #pragma unroll
        for (int r = 0; r < 4; r++) {
          int m = wm + sm * 16 + quad * 4 + r;
          int dst = rowinf[m];
          if (dst >= 0) {
            int col = bn + wn + sn * 16 + l16;
            size_t off = (size_t)dst * DMODEL + col;
            out[off] = acc[sm][sn][r] + x[off];
          }
        }
  }
}

extern "C" void kernel_launch(void* const* d_in, const int* in_sizes, int n_in,
                              void* d_out, int out_size, void* d_ws, size_t ws_size,
                              hipStream_t stream) {
  const float* x     = (const float*)d_in[0];
  const float* w_qkv = (const float*)d_in[1];
  const float* w_out = (const float*)d_in[2];
  const float* gamma = (const float*)d_in[3];
  const float* beta  = (const float*)d_in[4];
  const int*   ridx  = (const int*)d_in[5];
  float* out = (float*)d_out;

  char* ws = (char*)d_ws;
  size_t off = 0;
  auto alloc = [&](size_t bytes) {
    char* p = ws + off;
    off = (off + bytes + 255) & ~(size_t)255;
    return p;
  };
  unsigned short* xn   = (unsigned short*)alloc((size_t)ROWS * DMODEL * 2);     // 8 MB
  unsigned short* wqT  = (unsigned short*)alloc((size_t)QKVN * DMODEL * 2);     // 6 MB
  unsigned short* woT  = (unsigned short*)alloc((size_t)DMODEL * DMODEL * 2);   // 2 MB
  unsigned short* Wvs  = (unsigned short*)alloc((size_t)DMODEL * DMODEL * 2);   // 2 MB
  unsigned short* WvoT = (unsigned short*)alloc((size_t)DMODEL * DMODEL * 2);   // 2 MB
  unsigned short* xbar = (unsigned short*)alloc((size_t)ROWS * DMODEL * 2);     // 8 MB
  unsigned short* qf   = (unsigned short*)alloc((size_t)256 * DMODEL * 2);
  unsigned short* kf   = (unsigned short*)alloc((size_t)128 * DMODEL * 2);
  unsigned short* vf   = (unsigned short*)alloc((size_t)128 * DMODEL * 2);
  unsigned short* vbar = (unsigned short*)alloc((size_t)256 * DMODEL * 2);
  int* cols  = (int*)alloc((size_t)SEQ_ * 128 * 4);                             // 1 MB
  int* cnt   = (int*)alloc((size_t)SEQ_ * 4);
  int* tmx   = (int*)alloc((size_t)SEQ_ * 4);
  int* cnts2 = (int*)alloc((size_t)SEQ_ * 4);
  int* qlist = (int*)alloc(256 * 4);

  hipLaunchKernelGGL(k1_prep, dim3(4608), dim3(256), 0, stream,
                     x, w_qkv, w_out, gamma, beta, ridx,
                     xn, wqT, woT, Wvs, cols, cnt, tmx, cnts2, qlist);
  hipLaunchKernelGGL(k2_wgemm, dim3(192), dim3(256), 0, stream,
                     woT, Wvs, WvoT, xn, wqT, qlist, qf, kf, vf);
  hipLaunchKernelGGL(k3_xbar, dim3(1060), dim3(256), 0, stream,
                     xn, cols, cnt, tmx, cnts2, qlist, qf, kf, vf, xbar, vbar);
  hipLaunchKernelGGL(k4_final, dim3(272), dim3(256), 0, stream,
                     xbar, WvoT, vbar, woT, qlist, tmx, x, out);
}

// Round 11
// 155.980 us; speedup vs baseline: 1.0431x; 1.0431x over previous
//
#include <hip/hip_runtime.h>
#include <stdint.h>

typedef __attribute__((ext_vector_type(8))) short shortx8;
typedef __attribute__((ext_vector_type(4))) float floatx4;

static constexpr int SEQ_    = 2048;
static constexpr int DMODEL  = 1024;
static constexpr int HDIM    = 64;
static constexpr int BATCH_  = 2;
static constexpr int NHEADS  = 16;
static constexpr int WINDOW_ = 64;
static constexpr int GTOK    = 4;
static constexpr int RTOK    = 32;
static constexpr int ROWS    = BATCH_ * SEQ_;   // 4096
static constexpr int QKVN    = 3 * DMODEL;      // 3072

__device__ inline unsigned short f2bf(float f) {
  union { float f; unsigned int u; } x; x.f = f;
  unsigned int r = (x.u + 0x7FFFu + ((x.u >> 16) & 1u)) >> 16;
  return (unsigned short)r;
}
__device__ inline float bf2f(unsigned short b) {
  union { unsigned int u; float f; } x; x.u = ((unsigned int)b) << 16;
  return x.f;
}

__device__ inline void gload_lds16(const void* g, void* l) {
  __builtin_amdgcn_global_load_lds(
      (const __attribute__((address_space(1))) void*)g,
      (__attribute__((address_space(3))) void*)l, 16, 0, 0);
}

// ---- MFMA GEMM core: 128x64 tile, K=1024, BK=64, dbuf + COUNTED vmcnt (T4).
// Used by k2. Per K-step: STAGE(next) -> vmcnt(6) -> barrier -> COMPUTE -> barrier.
__device__ __forceinline__ void gemm_bk64_128x64(
    const unsigned short* __restrict__ aP0, const unsigned short* __restrict__ aP1,
    const unsigned short* __restrict__ aP2, const unsigned short* __restrict__ aP3,
    const unsigned short* __restrict__ bP0, const unsigned short* __restrict__ bP1,
    unsigned short* smem, const int wave, const int lane, floatx4 (&acc)[4][2]) {
  const int quad = lane >> 4, l16 = lane & 15;
  const int wm = (wave >> 1) * 64, wn = (wave & 1) * 32;
  const int h = l16 & 7;
  auto STAGE = [&](int c, int k0) {
    unsigned short* Ad = smem + c * 12288 + wave * 2048;          // 32 rows x 64
    unsigned short* Bd = smem + c * 12288 + 8192 + wave * 1024;   // 16 rows x 64
    gload_lds16(aP0 + k0, Ad);
    gload_lds16(aP1 + k0, Ad + 512);
    gload_lds16(aP2 + k0, Ad + 1024);
    gload_lds16(aP3 + k0, Ad + 1536);
    gload_lds16(bP0 + k0, Bd);
    gload_lds16(bP1 + k0, Bd + 512);
  };
  auto COMPUTE = [&](int c) {
    const unsigned short* A = smem + c * 12288;
    const unsigned short* B = A + 8192;
    #pragma unroll
    for (int kk = 0; kk < 2; kk++) {
      shortx8 af[4], bfr[2];
      #pragma unroll
      for (int s = 0; s < 4; s++)
        af[s] = *(const shortx8*)&A[(wm + s * 16 + l16) * 64 + (((quad + kk * 4) ^ h) * 8)];
      #pragma unroll
      for (int s = 0; s < 2; s++)
        bfr[s] = *(const shortx8*)&B[(wn + s * 16 + l16) * 64 + (((quad + kk * 4) ^ h) * 8)];
      #pragma unroll
      for (int sm = 0; sm < 4; sm++)
        #pragma unroll
        for (int sn = 0; sn < 2; sn++)
          acc[sm][sn] = __builtin_amdgcn_mfma_f32_16x16x32_bf16(af[sm], bfr[sn], acc[sm][sn], 0, 0, 0);
    }
  };
  STAGE(0, 0);
  int cur = 0;
  #pragma unroll 1
  for (int t = 0; t < 15; ++t) {
    STAGE(cur ^ 1, (t + 1) * 64);              // prefetch next tile (6 loads in flight)
    asm volatile("s_waitcnt vmcnt(6)" ::: "memory");   // prev tile's 6 loads landed
    __builtin_amdgcn_s_barrier();
    __builtin_amdgcn_sched_barrier(0);
    COMPUTE(cur);
    __builtin_amdgcn_sched_barrier(0);
    __builtin_amdgcn_s_barrier();
    cur ^= 1;
  }
  asm volatile("s_waitcnt vmcnt(0)" ::: "memory");
  __builtin_amdgcn_s_barrier();
  __builtin_amdgcn_sched_barrier(0);
  COMPUTE(cur);
}

// ---- MFMA GEMM core: 64x64 tile, K=1024, BK=64, dbuf + COUNTED vmcnt.
// Used by k4. 32 KB LDS; grid 1072 -> ~4 blocks/CU co-resident (the m114
// lever: other blocks' compute hides this block's per-step latency stall).
// Per wave: 4 staged loads/step (2 A 8-row groups, 2 B 8-row groups), vmcnt(4).
__device__ __forceinline__ void gemm_bk64_64x64(
    const unsigned short* __restrict__ aP0, const unsigned short* __restrict__ aP1,
    const unsigned short* __restrict__ bP0, const unsigned short* __restrict__ bP1,
    unsigned short* smem, const int wave, const int lane, floatx4 (&acc)[2][2]) {
  const int quad = lane >> 4, l16 = lane & 15;
  const int wm = (wave >> 1) * 32, wn = (wave & 1) * 32;
  const int h = l16 & 7;
  auto STAGE = [&](int c, int k0) {
    unsigned short* Ad = smem + c * 8192 + wave * 1024;          // 16 rows x 64
    unsigned short* Bd = smem + c * 8192 + 4096 + wave * 1024;   // 16 rows x 64
    gload_lds16(aP0 + k0, Ad);
    gload_lds16(aP1 + k0, Ad + 512);
    gload_lds16(bP0 + k0, Bd);
    gload_lds16(bP1 + k0, Bd + 512);
  };
  auto COMPUTE = [&](int c) {
    const unsigned short* A = smem + c * 8192;
    const unsigned short* B = A + 4096;
    #pragma unroll
    for (int kk = 0; kk < 2; kk++) {
      shortx8 af[2], bfr[2];
      #pragma unroll
      for (int s = 0; s < 2; s++)
        af[s] = *(const shortx8*)&A[(wm + s * 16 + l16) * 64 + (((quad + kk * 4) ^ h) * 8)];
      #pragma unroll
      for (int s = 0; s < 2; s++)
        bfr[s] = *(const shortx8*)&B[(wn + s * 16 + l16) * 64 + (((quad + kk * 4) ^ h) * 8)];
      #pragma unroll
      for (int sm = 0; sm < 2; sm++)
        #pragma unroll
        for (int sn = 0; sn < 2; sn++)
          acc[sm][sn] = __builtin_amdgcn_mfma_f32_16x16x32_bf16(af[sm], bfr[sn], acc[sm][sn], 0, 0, 0);
    }
  };
  STAGE(0, 0);
  int cur = 0;
  #pragma unroll 1
  for (int t = 0; t < 15; ++t) {
    STAGE(cur ^ 1, (t + 1) * 64);              // prefetch next tile (4 loads in flight)
    asm volatile("s_waitcnt vmcnt(4)" ::: "memory");   // prev tile's 4 loads landed
    __builtin_amdgcn_s_barrier();
    __builtin_amdgcn_sched_barrier(0);
    COMPUTE(cur);
    __builtin_amdgcn_sched_barrier(0);
    __builtin_amdgcn_s_barrier();
    cur ^= 1;
  }
  asm volatile("s_waitcnt vmcnt(0)" ::: "memory");
  __builtin_amdgcn_s_barrier();
  __builtin_amdgcn_sched_barrier(0);
  COMPUTE(cur);
}

// =================== K1: LN + weight converts + mask/tier lists ===================
// Compressed grid (4608): [0,1536) wqT 64k x 32n strips; [1536,2560) LN 1 row/wave;
// [2560,3072) woT 64k x 32n strips; [3072,3584) Wvs 32k x 64v uint stores;
// [3584,4608) mask/tier lists, 2 rows/block.
__global__ __launch_bounds__(256) void k1_prep(
    const float* __restrict__ x, const float* __restrict__ w_qkv,
    const float* __restrict__ w_out, const float* __restrict__ gamma,
    const float* __restrict__ beta, const int* __restrict__ ridx,
    unsigned short* __restrict__ xn, unsigned short* __restrict__ wqT,
    unsigned short* __restrict__ woT, unsigned short* __restrict__ Wvs,
    int* __restrict__ cols, int* __restrict__ cnt, int* __restrict__ tmx,
    int* __restrict__ cnts2, int* __restrict__ qlist) {
  __shared__ float tile[64][33];
  __shared__ int rl2[2][RTOK];
  __shared__ int scw2[2], scnw2[2], stm2[2];
  const int bx = blockIdx.x;
  const int t = threadIdx.x;
  if (bx < 1536) {
    // wqT: (K=1024 x N=3072) -> (N x K) bf16; strip = 64 k x 32 n
    const int n0 = (bx % 96) * 32, k0 = (bx / 96) * 64;
    const int tx = t & 31, ty = t >> 5;
    #pragma unroll
    for (int r = ty; r < 64; r += 8)
      tile[r][tx] = w_qkv[(size_t)(k0 + r) * QKVN + n0 + tx];
    __syncthreads();
    // stores: 32 lanes cover 64 k as uint pairs -> 128B contiguous segments
    #pragma unroll
    for (int r = ty; r < 32; r += 8) {
      unsigned int lo = f2bf(tile[2 * tx][r]);
      unsigned int hi = f2bf(tile[2 * tx + 1][r]);
      *(unsigned int*)&wqT[(size_t)(n0 + r) * DMODEL + k0 + 2 * tx] = lo | (hi << 16);
    }
  } else if (bx < 2560) {
    // LN: one row per wave (wave-local shfl reduction, no barriers)
    const int wave = t >> 6, lane = t & 63;
    const int row = (bx - 1536) * 4 + wave;
    const float4* xr = (const float4*)(x + (size_t)row * DMODEL);
    float4 v[4];
    #pragma unroll
    for (int j = 0; j < 4; j++) v[j] = xr[lane + j * 64];
    float s = 0.f;
    #pragma unroll
    for (int j = 0; j < 4; j++) s += v[j].x + v[j].y + v[j].z + v[j].w;
    #pragma unroll
    for (int o = 32; o > 0; o >>= 1) s += __shfl_xor(s, o);
    const float mean = s * (1.0f / DMODEL);
    float q = 0.f;
    #pragma unroll
    for (int j = 0; j < 4; j++) {
      float a = v[j].x - mean, b = v[j].y - mean, c = v[j].z - mean, d = v[j].w - mean;
      q += a * a + b * b + c * c + d * d;
    }
    #pragma unroll
    for (int o = 32; o > 0; o >>= 1) q += __shfl_xor(q, o);
    const float rs = rsqrtf(q * (1.0f / DMODEL) + 1e-5f);
    ushort4* xo = (ushort4*)(xn + (size_t)row * DMODEL);
    #pragma unroll
    for (int j = 0; j < 4; j++) {
      float4 g = ((const float4*)gamma)[lane + j * 64];
      float4 bb = ((const float4*)beta)[lane + j * 64];
      ushort4 ov;
      ov.x = f2bf((v[j].x - mean) * rs * g.x + bb.x);
      ov.y = f2bf((v[j].y - mean) * rs * g.y + bb.y);
      ov.z = f2bf((v[j].z - mean) * rs * g.z + bb.z);
      ov.w = f2bf((v[j].w - mean) * rs * g.w + bb.w);
      xo[lane + j * 64] = ov;
    }
  } else if (bx < 3072) {
    // woT: (K=1024 x N=1024) -> (N x K); strip = 64 k x 32 n
    const int idx = bx - 2560;
    const int n0 = (idx & 31) * 32, k0 = (idx >> 5) * 64;
    const int tx = t & 31, ty = t >> 5;
    #pragma unroll
    for (int r = ty; r < 64; r += 8)
      tile[r][tx] = w_out[(size_t)(k0 + r) * DMODEL + n0 + tx];
    __syncthreads();
    #pragma unroll
    for (int r = ty; r < 32; r += 8) {
      unsigned int lo = f2bf(tile[2 * tx][r]);
      unsigned int hi = f2bf(tile[2 * tx + 1][r]);
      *(unsigned int*)&woT[(size_t)(n0 + r) * DMODEL + k0 + 2 * tx] = lo | (hi << 16);
    }
  } else if (bx < 3584) {
    // Wvs convert: 32k x 64v strips, float2 loads + paired-uint stores
    const int idx = bx - 3072;
    const int v0 = (idx & 15) * 64, k0 = (idx >> 4) * 32;
    const int tx = t & 31, ty = t >> 5;
    #pragma unroll
    for (int r = ty; r < 32; r += 8) {
      const float2 w = *(const float2*)&w_qkv[(size_t)(k0 + r) * QKVN + 2 * DMODEL + v0 + 2 * tx];
      unsigned int lo = f2bf(w.x);
      unsigned int hi = f2bf(w.y);
      *(unsigned int*)&Wvs[(size_t)(k0 + r) * DMODEL + v0 + 2 * tx] = lo | (hi << 16);
    }
  } else {
    // masks: 2 rows per block (half = t>>7, c = t&127; all barriers block-uniform)
    const int h = t >> 7, c = t & 127;
    const int i = (bx - 3584) * 2 + h;
    if (c < RTOK) rl2[h][c] = ridx[i * RTOK + c];
    if (c == 0) { scw2[h] = 0; scnw2[h] = 0; stm2[h] = 0; }
    __syncthreads();
    const int wstart = (i - WINDOW_ > 0) ? (i - WINDOW_) : 0;
    int j = -1;
    bool valid = false;
    bool iswin = (c < 65);
    if (c < 65) {                       // window candidates (incl diagonal)
      j = i - WINDOW_ + c;
      valid = (j >= 0);
    } else if (c < 73) {                // global cols outside window
      int g = c - 65;
      j = (g < 4) ? g : (SEQ_ - 8 + g);
      valid = (j <= i) && (j < wstart);
    } else if (c < 73 + RTOK) {         // random cols outside window/global, deduped
      int r = c - 73;
      j = rl2[h][r];
      bool dup = false;
      for (int r2 = 0; r2 < r; r2++) dup = dup || (rl2[h][r2] == j);
      valid = (j <= i) && (j < wstart) && !(j < GTOK || j >= SEQ_ - GTOK) && !dup;
    }
    int tier = -1;
    if (valid) {
      int loc = ((i - j) <= WINDOW_) ? 1 : 0;
      int glb = (j < GTOK || j >= SEQ_ - GTOK) ? 1 : 0;
      int rnd = 0;
      for (int r = 0; r < RTOK; r++) rnd |= (rl2[h][r] == j) ? 1 : 0;
      tier = loc + glb + rnd;
      atomicMax(&stm2[h], tier);
    }
    __syncthreads();
    const int tm = stm2[h];
    if (valid && tier == tm) {
      if (iswin) {
        int pos = atomicAdd(&scw2[h], 1);
        cols[i * 128 + pos] = j;
      } else {
        int pos = 127 - atomicAdd(&scnw2[h], 1);
        cols[i * 128 + pos] = j;
      }
    }
    __syncthreads();
    if (c == 0) {
      cnt[i] = scw2[h] + scnw2[h];
      tmx[i] = tm;
      cnts2[i] = scw2[h] | (scnw2[h] << 16);
      if (i < 68 || i >= SEQ_ - 4) {
        int cc = (i < 68) ? i : 68 + (i - (SEQ_ - 4));
        qlist[cc * 2 + 0] = (tm == 3) ? i : -1;
        qlist[cc * 2 + 1] = (tm == 3) ? (SEQ_ + i) : -1;
      }
    }
  }
}

// =================== K2: Wvo weight-GEMM + tier-3 q/k/v gather-GEMMs ===============
__global__ __launch_bounds__(256) void k2_wgemm(
    const unsigned short* __restrict__ woT, const unsigned short* __restrict__ Wvs,
    unsigned short* __restrict__ WvoT, const unsigned short* __restrict__ xn,
    const unsigned short* __restrict__ wqT, const int* __restrict__ qlist,
    unsigned short* __restrict__ qf, unsigned short* __restrict__ kf,
    unsigned short* __restrict__ vf) {
  __shared__ __align__(16) unsigned short smem[2 * 12288];   // 48 KB dbuf
  const int bx = blockIdx.x, t = threadIdx.x;
  const int wave = t >> 6, lane = t & 63;
  const int quad = lane >> 4, l16 = lane & 15;
  const int wm = (wave >> 1) * 64, wn = (wave & 1) * 32;
  const int r8 = lane >> 3;
  const int swo = ((lane & 7) ^ r8) * 8;     // inverse-swizzled source chunk
  floatx4 acc[4][2] = {};
  if (bx < 128) {
    const int bm = (bx >> 4) * 128, bn = (bx & 15) * 64;
    const unsigned short* a0 = woT + (size_t)(bm + wave * 32 + r8) * DMODEL + swo;
    const unsigned short* b0 = Wvs + (size_t)(bn + wave * 16 + r8) * DMODEL + swo;
    gemm_bk64_128x64(a0, a0 + 8 * DMODEL, a0 + 16 * DMODEL, a0 + 24 * DMODEL,
                     b0, b0 + 8 * DMODEL, smem, wave, lane, acc);
    #pragma unroll
    for (int sm = 0; sm < 4; sm++)
      #pragma unroll
      for (int sn = 0; sn < 2; sn++)
        #pragma unroll
        for (int r = 0; r < 4; r++) {
          int row = bm + wm + sm * 16 + quad * 4 + r;
          int col = bn + wn + sn * 16 + l16;
          WvoT[(size_t)row * DMODEL + col] = f2bf(acc[sm][sn][r]);
        }
  } else {
    const int idx = bx - 128;
    const int job = idx >> 4, bn = (idx & 15) * 64;
    const int wsel = (job < 2) ? 0 : ((job == 2) ? 1 : 2);
    const unsigned short* BT = wqT + (size_t)wsel * DMODEL * DMODEL;
    unsigned short* dstbuf = (job == 0) ? qf
                           : (job == 1) ? (qf + (size_t)128 * DMODEL)
                           : (job == 2) ? kf : vf;
    const unsigned short* aPg[4];
    #pragma unroll
    for (int g = 0; g < 4; g++) {
      int m = wave * 32 + g * 8 + r8;        // 0..127 within tile (per-lane row)
      int row;
      if (job < 2) {
        int s = job * 128 + m;
        int ql = (s < 144) ? qlist[s] : -1;
        row = (ql < 0) ? 0 : ql;
      } else {
        row = (m < 16) ? ((m >> 3) * SEQ_ + (((m & 7) < 4) ? (m & 7) : (SEQ_ - 8 + (m & 7)))) : 0;
      }
      aPg[g] = xn + (size_t)row * DMODEL + swo;
    }
    const unsigned short* b0 = BT + (size_t)(bn + wave * 16 + r8) * DMODEL + swo;
    gemm_bk64_128x64(aPg[0], aPg[1], aPg[2], aPg[3],
                     b0, b0 + 8 * DMODEL, smem, wave, lane, acc);
    #pragma unroll
    for (int sm = 0; sm < 4; sm++)
      #pragma unroll
      for (int sn = 0; sn < 2; sn++)
        #pragma unroll
        for (int r = 0; r < 4; r++) {
          int m = wm + sm * 16 + quad * 4 + r;
          int col = bn + wn + sn * 16 + l16;
          dstbuf[(size_t)m * DMODEL + col] = f2bf(acc[sm][sn][r]);
        }
  }
}

// =================== K3: tier-3 softmax (first) + sliding-window xbar ==============
__global__ __launch_bounds__(256) void k3_xbar(
    const unsigned short* __restrict__ xn, const int* __restrict__ cols,
    const int* __restrict__ cnt, const int* __restrict__ tmx,
    const int* __restrict__ cnts2, const int* __restrict__ qlist,
    const unsigned short* __restrict__ qf, const unsigned short* __restrict__ kf,
    const unsigned short* __restrict__ vf,
    unsigned short* __restrict__ xbar, unsigned short* __restrict__ vbar) {
  const int bx = blockIdx.x, t = threadIdx.x;
  const int wave = t >> 6, lane = t & 63;
  if (bx >= 36) {
    __shared__ unsigned short win[80][256];   // rows [i0-64, i0+15] x 256 dims
    const int xb = bx - 36;
    const int b = xb >> 9, rest = xb & 511;
    const int i0 = (rest >> 2) * 16, dimbase = (rest & 3) * 256;
    const size_t xnb = (size_t)(b * SEQ_) * DMODEL;
    const int lo = i0 - 64;
    const int r0 = i0 + wave * 4;
    // ---- preload metadata for this wave's 4 rows (coalesced, before chains) ----
    int tm_[4], cw_[4], cnw_[4], jr0_[4], jr1_[4];
    #pragma unroll
    for (int rr = 0; rr < 4; rr++) {
      const int i = r0 + rr;
      tm_[rr] = tmx[i];
      int c2 = cnts2[i];
      cw_[rr] = c2 & 0xffff; cnw_[rr] = c2 >> 16;
      jr0_[rr] = cols[i * 128 + lane];
      jr1_[rr] = cols[i * 128 + 64 + lane];
    }
    // ---- stage 80 window rows, int4/lane: 2 rows per wave-iter ----
    {
      const int l5 = lane & 31, rsub = lane >> 5;
      #pragma unroll 5
      for (int it = 0; it < 10; it++) {
        int r = it * 8 + wave * 2 + rsub;
        int gr = lo + r;
        if (gr >= 0)
          *(int4*)&win[r][l5 * 8] =
              *(const int4*)(xn + xnb + (size_t)gr * DMODEL + dimbase + l5 * 8);
      }
    }
    __syncthreads();
    const unsigned short* xnd = xn + xnb + dimbase + lane * 4;
    auto add4 = [](float4& s, ushort4 v) {
      s.x += bf2f(v.x); s.y += bf2f(v.y); s.z += bf2f(v.z); s.w += bf2f(v.w);
    };
    auto sub4 = [](float4& s, ushort4 v) {
      s.x -= bf2f(v.x); s.y -= bf2f(v.y); s.z -= bf2f(v.z); s.w -= bf2f(v.w);
    };
    // ---- init sliding window sum for row r0: rows [max(0,r0-64), r0] ----
    float4 ws = {0, 0, 0, 0};
    {
      float4 t1 = {0,0,0,0}, t2 = {0,0,0,0}, t3 = {0,0,0,0};
      const int jstart = (r0 - 64 > 0) ? (r0 - 64) : 0;
      const int cn = r0 - jstart + 1;
      const int base = jstart - lo;
      int c = 0;
      for (; c + 4 <= cn; c += 4) {
        ushort4 v0 = *(const ushort4*)&win[base + c][lane * 4];
        ushort4 v1 = *(const ushort4*)&win[base + c + 1][lane * 4];
        ushort4 v2 = *(const ushort4*)&win[base + c + 2][lane * 4];
        ushort4 v3 = *(const ushort4*)&win[base + c + 3][lane * 4];
        add4(ws, v0); add4(t1, v1); add4(t2, v2); add4(t3, v3);
      }
      for (; c < cn; c++) add4(ws, *(const ushort4*)&win[base + c][lane * 4]);
      ws.x += t1.x + t2.x + t3.x; ws.y += t1.y + t2.y + t3.y;
      ws.z += t1.z + t2.z + t3.z; ws.w += t1.w + t2.w + t3.w;
    }
    for (int rr = 0; rr < 4; rr++) {
      const int i = r0 + rr;
      if (rr > 0) {   // slide: add row i, drop row i-65
        add4(ws, *(const ushort4*)&win[i - lo][lane * 4]);
        int dj = i - 65;
        if (dj >= 0) sub4(ws, *(const ushort4*)&win[dj - lo][lane * 4]);
      }
      const int tm = tm_[rr];
      ushort4 o;
      if (tm == 3) {
        o.x = o.y = o.z = o.w = 0;
      } else {
        const int cw = cw_[rr], cnw = cnw_[rr];
        const int jr1 = jr1_[rr];
        float4 s;
        if (tm == 1) {
          // s = ws + gather of cnw non-window cols; branchless global, 8-deep ILP
          s = ws;
          float4 t1 = {0,0,0,0}, t2 = {0,0,0,0}, t3 = {0,0,0,0};
          const int bb = 64 - cnw;
          int c = 0;
          for (; c + 8 <= cnw; c += 8) {
            ushort4 v0 = *(const ushort4*)(xnd + (size_t)__shfl(jr1, bb + c)     * DMODEL);
            ushort4 v1 = *(const ushort4*)(xnd + (size_t)__shfl(jr1, bb + c + 1) * DMODEL);
            ushort4 v2 = *(const ushort4*)(xnd + (size_t)__shfl(jr1, bb + c + 2) * DMODEL);
            ushort4 v3 = *(const ushort4*)(xnd + (size_t)__shfl(jr1, bb + c + 3) * DMODEL);
            ushort4 v4 = *(const ushort4*)(xnd + (size_t)__shfl(jr1, bb + c + 4) * DMODEL);
            ushort4 v5 = *(const ushort4*)(xnd + (size_t)__shfl(jr1, bb + c + 5) * DMODEL);
            ushort4 v6 = *(const ushort4*)(xnd + (size_t)__shfl(jr1, bb + c + 6) * DMODEL);
            ushort4 v7 = *(const ushort4*)(xnd + (size_t)__shfl(jr1, bb + c + 7) * DMODEL);
            add4(s, v0); add4(t1, v1); add4(t2, v2); add4(t3, v3);
            add4(s, v4); add4(t1, v5); add4(t2, v6); add4(t3, v7);
          }
          if (c + 4 <= cnw) {
            ushort4 v0 = *(const ushort4*)(xnd + (size_t)__shfl(jr1, bb + c)     * DMODEL);
            ushort4 v1 = *(const ushort4*)(xnd + (size_t)__shfl(jr1, bb + c + 1) * DMODEL);
            ushort4 v2 = *(const ushort4*)(xnd + (size_t)__shfl(jr1, bb + c + 2) * DMODEL);
            ushort4 v3 = *(const ushort4*)(xnd + (size_t)__shfl(jr1, bb + c + 3) * DMODEL);
            add4(s, v0); add4(t1, v1); add4(t2, v2); add4(t3, v3);
            c += 4;
          }
          for (; c < cnw; c++)
            add4(s, *(const ushort4*)(xnd + (size_t)__shfl(jr1, bb + c) * DMODEL));
          s.x += t1.x + t2.x + t3.x; s.y += t1.y + t2.y + t3.y;
          s.z += t1.z + t2.z + t3.z; s.w += t1.w + t2.w + t3.w;
        } else {      // tm == 2: small n, branchless global gathers
          const int jr0 = jr0_[rr];
          s.x = s.y = s.z = s.w = 0.f;
          for (int c = 0; c < cw; c++) {
            int j = (c < 64) ? __shfl(jr0, c) : __shfl(jr1, c - 64);
            add4(s, *(const ushort4*)(xnd + (size_t)j * DMODEL));
          }
          const int bb = 64 - cnw;
          for (int c = 0; c < cnw; c++)
            add4(s, *(const ushort4*)(xnd + (size_t)__shfl(jr1, bb + c) * DMODEL));
        }
        const float inv = 1.0f / (float)(cw + cnw);
        o.x = f2bf(s.x * inv); o.y = f2bf(s.y * inv);
        o.z = f2bf(s.z * inv); o.w = f2bf(s.w * inv);
      }
      *(ushort4*)(xbar + (size_t)(b * SEQ_ + i) * DMODEL + dimbase + lane * 4) = o;
    }
  } else {
    const int s = bx * 4 + wave;                // slot in [0,144)
    const int dst = (s < 144) ? qlist[s] : -1;
    if (dst < 0) return;
    const int b = dst >> 11, i = dst & (SEQ_ - 1);
    const int n = cnt[i];                       // tier-3 cols all in lower segment
    int myk = 0;
    if (lane < n) {
      int kj = cols[i * 128 + lane];
      myk = b * 8 + ((kj < 4) ? kj : (kj - (SEQ_ - 8)));
    }
    for (int h = 0; h < NHEADS; h++) {
      float qd = bf2f(qf[(size_t)s * DMODEL + h * HDIM + lane]);
      float w[8];
      float m = -1e30f;
      for (int c = 0; c < n; c++) {
        int ks = __shfl(myk, c);
        float kd = bf2f(kf[(size_t)ks * DMODEL + h * HDIM + lane]);
        float p = qd * kd;
        #pragma unroll
        for (int o = 32; o > 0; o >>= 1) p += __shfl_xor(p, o);
        p *= 0.375f;                    // 3 * (q.k / 8)
        w[c] = p;
        m = fmaxf(m, p);
      }
      float denom = 0.f, acc = 0.f;
      for (int c = 0; c < n; c++) {
        int ks = __shfl(myk, c);
        float e = __expf(w[c] - m);
        denom += e;
        acc += e * bf2f(vf[(size_t)ks * DMODEL + h * HDIM + lane]);
      }
      vbar[(size_t)s * DMODEL + h * HDIM + lane] = f2bf(acc / denom);
    }
  }
}

// =================== K4: main fused GEMM (64x64 tiles) + tier-3 fixup GEMM =========
__global__ __launch_bounds__(256) void k4_final(
    const unsigned short* __restrict__ xbar, const unsigned short* __restrict__ WvoT,
    const unsigned short* __restrict__ vbar, const unsigned short* __restrict__ woT,
    const int* __restrict__ qlist, const int* __restrict__ tmx,
    const float* __restrict__ x, float* __restrict__ out) {
  __shared__ __align__(16) unsigned short smem[2 * 8192];   // 32 KB dbuf
  __shared__ int rowinf[64];
  const int bx = blockIdx.x, t = threadIdx.x;
  const int wave = t >> 6, lane = t & 63;
  const int quad = lane >> 4, l16 = lane & 15;
  const int wm = (wave >> 1) * 32, wn = (wave & 1) * 32;
  const int r8 = lane >> 3;
  const int swo = ((lane & 7) ^ r8) * 8;
  floatx4 acc[2][2] = {};
  if (bx < 1024) {
    // bijective XCD swizzle (1024 % 8 == 0): each XCD owns 8 contiguous A
    // row-panels (1 MB) + WvoT (2 MB) -> redundant panel reads are L2-hits (T1)
    const int bs = (bx & 7) * 128 + (bx >> 3);
    const int bm = (bs >> 4) * 64, bn = (bs & 15) * 64;
    if (t < 64) rowinf[t] = tmx[(bm + t) & (SEQ_ - 1)];
    const unsigned short* a0 = xbar + (size_t)(bm + wave * 16 + r8) * DMODEL + swo;
    const unsigned short* b0 = WvoT + (size_t)(bn + wave * 16 + r8) * DMODEL + swo;
    gemm_bk64_64x64(a0, a0 + 8 * DMODEL, b0, b0 + 8 * DMODEL, smem, wave, lane, acc);
    #pragma unroll
    for (int sm = 0; sm < 2; sm++)
      #pragma unroll
      for (int sn = 0; sn < 2; sn++)
        #pragma unroll
        for (int r = 0; r < 4; r++) {
          int m = wm + sm * 16 + quad * 4 + r;
          if (rowinf[m] != 3) {
            int col = bn + wn + sn * 16 + l16;
            size_t off = (size_t)(bm + m) * DMODEL + col;
            out[off] = acc[sm][sn][r] + x[off];
          }
        }
  } else {
    const int idx = bx - 1024;                   // [0,48): 3 row-blocks x 16 cols
    const int bm = (idx >> 4) * 64, bn = (idx & 15) * 64;
    if (t < 64) {
      int s = bm + t;
      rowinf[t] = (s < 144) ? qlist[s] : -1;
    }
    const unsigned short* a0 = vbar + (size_t)(bm + wave * 16 + r8) * DMODEL + swo;
    const unsigned short* b0 = woT + (size_t)(bn + wave * 16 + r8) * DMODEL + swo;
    gemm_bk64_64x64(a0, a0 + 8 * DMODEL, b0, b0 + 8 * DMODEL, smem, wave, lane, acc);
    #pragma unroll
    for (int sm = 0; sm < 2; sm++)
      #pragma unroll
      for (int sn = 0; sn < 2; sn++)
        #pragma unroll
        for (int r = 0; r < 4; r++) {
          int m = wm + sm * 16 + quad * 4 + r;
          int dst = rowinf[m];
          if (dst >= 0) {
            int col = bn + wn + sn * 16 + l16;
            size_t off = (size_t)dst * DMODEL + col;
            out[off] = acc[sm][sn][r] + x[off];
          }
        }
  }
}

extern "C" void kernel_launch(void* const* d_in, const int* in_sizes, int n_in,
                              void* d_out, int out_size, void* d_ws, size_t ws_size,
                              hipStream_t stream) {
  const float* x     = (const float*)d_in[0];
  const float* w_qkv = (const float*)d_in[1];
  const float* w_out = (const float*)d_in[2];
  const float* gamma = (const float*)d_in[3];
  const float* beta  = (const float*)d_in[4];
  const int*   ridx  = (const int*)d_in[5];
  float* out = (float*)d_out;

  char* ws = (char*)d_ws;
  size_t off = 0;
  auto alloc = [&](size_t bytes) {
    char* p = ws + off;
    off = (off + bytes + 255) & ~(size_t)255;
    return p;
  };
  unsigned short* xn   = (unsigned short*)alloc((size_t)ROWS * DMODEL * 2);     // 8 MB
  unsigned short* wqT  = (unsigned short*)alloc((size_t)QKVN * DMODEL * 2);     // 6 MB
  unsigned short* woT  = (unsigned short*)alloc((size_t)DMODEL * DMODEL * 2);   // 2 MB
  unsigned short* Wvs  = (unsigned short*)alloc((size_t)DMODEL * DMODEL * 2);   // 2 MB
  unsigned short* WvoT = (unsigned short*)alloc((size_t)DMODEL * DMODEL * 2);   // 2 MB
  unsigned short* xbar = (unsigned short*)alloc((size_t)ROWS * DMODEL * 2);     // 8 MB
  unsigned short* qf   = (unsigned short*)alloc((size_t)256 * DMODEL * 2);
  unsigned short* kf   = (unsigned short*)alloc((size_t)128 * DMODEL * 2);
  unsigned short* vf   = (unsigned short*)alloc((size_t)128 * DMODEL * 2);
  unsigned short* vbar = (unsigned short*)alloc((size_t)256 * DMODEL * 2);
  int* cols  = (int*)alloc((size_t)SEQ_ * 128 * 4);                             // 1 MB
  int* cnt   = (int*)alloc((size_t)SEQ_ * 4);
  int* tmx   = (int*)alloc((size_t)SEQ_ * 4);
  int* cnts2 = (int*)alloc((size_t)SEQ_ * 4);
  int* qlist = (int*)alloc(256 * 4);

  hipLaunchKernelGGL(k1_prep, dim3(4608), dim3(256), 0, stream,
                     x, w_qkv, w_out, gamma, beta, ridx,
                     xn, wqT, woT, Wvs, cols, cnt, tmx, cnts2, qlist);
  hipLaunchKernelGGL(k2_wgemm, dim3(192), dim3(256), 0, stream,
                     woT, Wvs, WvoT, xn, wqT, qlist, qf, kf, vf);
  hipLaunchKernelGGL(k3_xbar, dim3(1060), dim3(256), 0, stream,
                     xn, cols, cnt, tmx, cnts2, qlist, qf, kf, vf, xbar, vbar);
  hipLaunchKernelGGL(k4_final, dim3(1072), dim3(256), 0, stream,
                     xbar, WvoT, vbar, woT, qlist, tmx, x, out);
}

// Round 12
// 153.946 us; speedup vs baseline: 1.0569x; 1.0132x over previous
//
#include <hip/hip_runtime.h>
#include <stdint.h>

typedef __attribute__((ext_vector_type(8))) short shortx8;
typedef __attribute__((ext_vector_type(4))) float floatx4;

static constexpr int SEQ_    = 2048;
static constexpr int DMODEL  = 1024;
static constexpr int HDIM    = 64;
static constexpr int BATCH_  = 2;
static constexpr int NHEADS  = 16;
static constexpr int WINDOW_ = 64;
static constexpr int GTOK    = 4;
static constexpr int RTOK    = 32;
static constexpr int ROWS    = BATCH_ * SEQ_;   // 4096
static constexpr int QKVN    = 3 * DMODEL;      // 3072

__device__ inline unsigned short f2bf(float f) {
  union { float f; unsigned int u; } x; x.f = f;
  unsigned int r = (x.u + 0x7FFFu + ((x.u >> 16) & 1u)) >> 16;
  return (unsigned short)r;
}
__device__ inline float bf2f(unsigned short b) {
  union { unsigned int u; float f; } x; x.u = ((unsigned int)b) << 16;
  return x.f;
}

__device__ inline void gload_lds16(const void* g, void* l) {
  __builtin_amdgcn_global_load_lds(
      (const __attribute__((address_space(1))) void*)g,
      (__attribute__((address_space(3))) void*)l, 16, 0, 0);
}

// ---- MFMA GEMM core: 128x64 tile, K=1024, BK=64, dbuf + COUNTED vmcnt (T4).
// Used by k2. Per K-step: STAGE(next) -> vmcnt(6) -> barrier -> COMPUTE -> barrier.
__device__ __forceinline__ void gemm_bk64_128x64(
    const unsigned short* __restrict__ aP0, const unsigned short* __restrict__ aP1,
    const unsigned short* __restrict__ aP2, const unsigned short* __restrict__ aP3,
    const unsigned short* __restrict__ bP0, const unsigned short* __restrict__ bP1,
    unsigned short* smem, const int wave, const int lane, floatx4 (&acc)[4][2]) {
  const int quad = lane >> 4, l16 = lane & 15;
  const int wm = (wave >> 1) * 64, wn = (wave & 1) * 32;
  const int h = l16 & 7;
  auto STAGE = [&](int c, int k0) {
    unsigned short* Ad = smem + c * 12288 + wave * 2048;          // 32 rows x 64
    unsigned short* Bd = smem + c * 12288 + 8192 + wave * 1024;   // 16 rows x 64
    gload_lds16(aP0 + k0, Ad);
    gload_lds16(aP1 + k0, Ad + 512);
    gload_lds16(aP2 + k0, Ad + 1024);
    gload_lds16(aP3 + k0, Ad + 1536);
    gload_lds16(bP0 + k0, Bd);
    gload_lds16(bP1 + k0, Bd + 512);
  };
  auto COMPUTE = [&](int c) {
    const unsigned short* A = smem + c * 12288;
    const unsigned short* B = A + 8192;
    #pragma unroll
    for (int kk = 0; kk < 2; kk++) {
      shortx8 af[4], bfr[2];
      #pragma unroll
      for (int s = 0; s < 4; s++)
        af[s] = *(const shortx8*)&A[(wm + s * 16 + l16) * 64 + (((quad + kk * 4) ^ h) * 8)];
      #pragma unroll
      for (int s = 0; s < 2; s++)
        bfr[s] = *(const shortx8*)&B[(wn + s * 16 + l16) * 64 + (((quad + kk * 4) ^ h) * 8)];
      #pragma unroll
      for (int sm = 0; sm < 4; sm++)
        #pragma unroll
        for (int sn = 0; sn < 2; sn++)
          acc[sm][sn] = __builtin_amdgcn_mfma_f32_16x16x32_bf16(af[sm], bfr[sn], acc[sm][sn], 0, 0, 0);
    }
  };
  STAGE(0, 0);
  int cur = 0;
  #pragma unroll 1
  for (int t = 0; t < 15; ++t) {
    STAGE(cur ^ 1, (t + 1) * 64);              // prefetch next tile (6 loads in flight)
    asm volatile("s_waitcnt vmcnt(6)" ::: "memory");   // prev tile's 6 loads landed
    __builtin_amdgcn_s_barrier();
    __builtin_amdgcn_sched_barrier(0);
    COMPUTE(cur);
    __builtin_amdgcn_sched_barrier(0);
    __builtin_amdgcn_s_barrier();
    cur ^= 1;
  }
  asm volatile("s_waitcnt vmcnt(0)" ::: "memory");
  __builtin_amdgcn_s_barrier();
  __builtin_amdgcn_sched_barrier(0);
  COMPUTE(cur);
}

// ---- MFMA GEMM core: 64x64 tile, K=1024, BK=64, 3-DEEP pipeline + counted vmcnt.
// Used by k4. 48 KB LDS (3 x 16 KB buffers) -> 3 blocks/CU. Per iteration:
// STAGE(tile t+2) then vmcnt(8) -- only tile t's 4 loads must have landed; 8
// loads (t+1, t+2) stay in flight ACROSS the barriers. Wait-for distance grows
// from ~1 COMPUTE phase to ~2 phases (~500cy), covering L2-hit (~200cy) fully
// and most of HBM (~900cy) first-touch latency. WAR: STAGE(t+2) overwrites the
// buffer COMPUTE(t-1) read; the end-of-iter barrier at t-1 ordered those reads.
__device__ __forceinline__ void gemm_bk64_64x64_p3(
    const unsigned short* __restrict__ aP0, const unsigned short* __restrict__ aP1,
    const unsigned short* __restrict__ bP0, const unsigned short* __restrict__ bP1,
    unsigned short* smem, const int wave, const int lane, floatx4 (&acc)[2][2]) {
  const int quad = lane >> 4, l16 = lane & 15;
  const int wm = (wave >> 1) * 32, wn = (wave & 1) * 32;
  const int h = l16 & 7;
  auto STAGE = [&](int c, int k0) {
    unsigned short* Ad = smem + c * 8192 + wave * 1024;          // 16 rows x 64
    unsigned short* Bd = smem + c * 8192 + 4096 + wave * 1024;   // 16 rows x 64
    gload_lds16(aP0 + k0, Ad);
    gload_lds16(aP1 + k0, Ad + 512);
    gload_lds16(bP0 + k0, Bd);
    gload_lds16(bP1 + k0, Bd + 512);
  };
  auto COMPUTE = [&](int c) {
    const unsigned short* A = smem + c * 8192;
    const unsigned short* B = A + 4096;
    #pragma unroll
    for (int kk = 0; kk < 2; kk++) {
      shortx8 af[2], bfr[2];
      #pragma unroll
      for (int s = 0; s < 2; s++)
        af[s] = *(const shortx8*)&A[(wm + s * 16 + l16) * 64 + (((quad + kk * 4) ^ h) * 8)];
      #pragma unroll
      for (int s = 0; s < 2; s++)
        bfr[s] = *(const shortx8*)&B[(wn + s * 16 + l16) * 64 + (((quad + kk * 4) ^ h) * 8)];
      #pragma unroll
      for (int sm = 0; sm < 2; sm++)
        #pragma unroll
        for (int sn = 0; sn < 2; sn++)
          acc[sm][sn] = __builtin_amdgcn_mfma_f32_16x16x32_bf16(af[sm], bfr[sn], acc[sm][sn], 0, 0, 0);
    }
  };
  STAGE(0, 0);                                  // tile 0 -> buf 0 (4 loads)
  STAGE(1, 64);                                 // tile 1 -> buf 1 (8 in flight)
  int cs = 2, cc = 0;
  #pragma unroll 1
  for (int t = 0; t < 14; ++t) {
    STAGE(cs, (t + 2) * 64);                    // tile t+2 (12 in flight)
    cs = (cs == 2) ? 0 : cs + 1;
    asm volatile("s_waitcnt vmcnt(8)" ::: "memory");   // tile t's 4 loads landed
    __builtin_amdgcn_s_barrier();
    __builtin_amdgcn_sched_barrier(0);
    COMPUTE(cc);                                // tile t
    cc = (cc == 2) ? 0 : cc + 1;
    __builtin_amdgcn_sched_barrier(0);
    __builtin_amdgcn_s_barrier();
  }
  asm volatile("s_waitcnt vmcnt(4)" ::: "memory");     // tile 14's loads landed
  __builtin_amdgcn_s_barrier();
  __builtin_amdgcn_sched_barrier(0);
  COMPUTE(cc);                                  // tile 14
  cc = (cc == 2) ? 0 : cc + 1;
  __builtin_amdgcn_sched_barrier(0);
  __builtin_amdgcn_s_barrier();
  asm volatile("s_waitcnt vmcnt(0)" ::: "memory");     // tile 15's loads landed
  __builtin_amdgcn_s_barrier();
  __builtin_amdgcn_sched_barrier(0);
  COMPUTE(cc);                                  // tile 15
}

// =================== K1: LN + weight converts + mask/tier lists ===================
// Compressed grid (4608): [0,1536) wqT 64k x 32n strips; [1536,2560) LN 1 row/wave;
// [2560,3072) woT 64k x 32n strips; [3072,3584) Wvs 32k x 64v uint stores;
// [3584,4608) mask/tier lists, 2 rows/block.
__global__ __launch_bounds__(256) void k1_prep(
    const float* __restrict__ x, const float* __restrict__ w_qkv,
    const float* __restrict__ w_out, const float* __restrict__ gamma,
    const float* __restrict__ beta, const int* __restrict__ ridx,
    unsigned short* __restrict__ xn, unsigned short* __restrict__ wqT,
    unsigned short* __restrict__ woT, unsigned short* __restrict__ Wvs,
    int* __restrict__ cols, int* __restrict__ cnt, int* __restrict__ tmx,
    int* __restrict__ cnts2, int* __restrict__ qlist) {
  __shared__ float tile[64][33];
  __shared__ int rl2[2][RTOK];
  __shared__ int scw2[2], scnw2[2], stm2[2];
  const int bx = blockIdx.x;
  const int t = threadIdx.x;
  if (bx < 1536) {
    // wqT: (K=1024 x N=3072) -> (N x K) bf16; strip = 64 k x 32 n
    const int n0 = (bx % 96) * 32, k0 = (bx / 96) * 64;
    const int tx = t & 31, ty = t >> 5;
    #pragma unroll
    for (int r = ty; r < 64; r += 8)
      tile[r][tx] = w_qkv[(size_t)(k0 + r) * QKVN + n0 + tx];
    __syncthreads();
    // stores: 32 lanes cover 64 k as uint pairs -> 128B contiguous segments
    #pragma unroll
    for (int r = ty; r < 32; r += 8) {
      unsigned int lo = f2bf(tile[2 * tx][r]);
      unsigned int hi = f2bf(tile[2 * tx + 1][r]);
      *(unsigned int*)&wqT[(size_t)(n0 + r) * DMODEL + k0 + 2 * tx] = lo | (hi << 16);
    }
  } else if (bx < 2560) {
    // LN: one row per wave (wave-local shfl reduction, no barriers)
    const int wave = t >> 6, lane = t & 63;
    const int row = (bx - 1536) * 4 + wave;
    const float4* xr = (const float4*)(x + (size_t)row * DMODEL);
    float4 v[4];
    #pragma unroll
    for (int j = 0; j < 4; j++) v[j] = xr[lane + j * 64];
    float s = 0.f;
    #pragma unroll
    for (int j = 0; j < 4; j++) s += v[j].x + v[j].y + v[j].z + v[j].w;
    #pragma unroll
    for (int o = 32; o > 0; o >>= 1) s += __shfl_xor(s, o);
    const float mean = s * (1.0f / DMODEL);
    float q = 0.f;
    #pragma unroll
    for (int j = 0; j < 4; j++) {
      float a = v[j].x - mean, b = v[j].y - mean, c = v[j].z - mean, d = v[j].w - mean;
      q += a * a + b * b + c * c + d * d;
    }
    #pragma unroll
    for (int o = 32; o > 0; o >>= 1) q += __shfl_xor(q, o);
    const float rs = rsqrtf(q * (1.0f / DMODEL) + 1e-5f);
    ushort4* xo = (ushort4*)(xn + (size_t)row * DMODEL);
    #pragma unroll
    for (int j = 0; j < 4; j++) {
      float4 g = ((const float4*)gamma)[lane + j * 64];
      float4 bb = ((const float4*)beta)[lane + j * 64];
      ushort4 ov;
      ov.x = f2bf((v[j].x - mean) * rs * g.x + bb.x);
      ov.y = f2bf((v[j].y - mean) * rs * g.y + bb.y);
      ov.z = f2bf((v[j].z - mean) * rs * g.z + bb.z);
      ov.w = f2bf((v[j].w - mean) * rs * g.w + bb.w);
      xo[lane + j * 64] = ov;
    }
  } else if (bx < 3072) {
    // woT: (K=1024 x N=1024) -> (N x K); strip = 64 k x 32 n
    const int idx = bx - 2560;
    const int n0 = (idx & 31) * 32, k0 = (idx >> 5) * 64;
    const int tx = t & 31, ty = t >> 5;
    #pragma unroll
    for (int r = ty; r < 64; r += 8)
      tile[r][tx] = w_out[(size_t)(k0 + r) * DMODEL + n0 + tx];
    __syncthreads();
    #pragma unroll
    for (int r = ty; r < 32; r += 8) {
      unsigned int lo = f2bf(tile[2 * tx][r]);
      unsigned int hi = f2bf(tile[2 * tx + 1][r]);
      *(unsigned int*)&woT[(size_t)(n0 + r) * DMODEL + k0 + 2 * tx] = lo | (hi << 16);
    }
  } else if (bx < 3584) {
    // Wvs convert: 32k x 64v strips, float2 loads + paired-uint stores
    const int idx = bx - 3072;
    const int v0 = (idx & 15) * 64, k0 = (idx >> 4) * 32;
    const int tx = t & 31, ty = t >> 5;
    #pragma unroll
    for (int r = ty; r < 32; r += 8) {
      const float2 w = *(const float2*)&w_qkv[(size_t)(k0 + r) * QKVN + 2 * DMODEL + v0 + 2 * tx];
      unsigned int lo = f2bf(w.x);
      unsigned int hi = f2bf(w.y);
      *(unsigned int*)&Wvs[(size_t)(k0 + r) * DMODEL + v0 + 2 * tx] = lo | (hi << 16);
    }
  } else {
    // masks: 2 rows per block (half = t>>7, c = t&127; all barriers block-uniform)
    const int h = t >> 7, c = t & 127;
    const int i = (bx - 3584) * 2 + h;
    if (c < RTOK) rl2[h][c] = ridx[i * RTOK + c];
    if (c == 0) { scw2[h] = 0; scnw2[h] = 0; stm2[h] = 0; }
    __syncthreads();
    const int wstart = (i - WINDOW_ > 0) ? (i - WINDOW_) : 0;
    int j = -1;
    bool valid = false;
    bool iswin = (c < 65);
    if (c < 65) {                       // window candidates (incl diagonal)
      j = i - WINDOW_ + c;
      valid = (j >= 0);
    } else if (c < 73) {                // global cols outside window
      int g = c - 65;
      j = (g < 4) ? g : (SEQ_ - 8 + g);
      valid = (j <= i) && (j < wstart);
    } else if (c < 73 + RTOK) {         // random cols outside window/global, deduped
      int r = c - 73;
      j = rl2[h][r];
      bool dup = false;
      for (int r2 = 0; r2 < r; r2++) dup = dup || (rl2[h][r2] == j);
      valid = (j <= i) && (j < wstart) && !(j < GTOK || j >= SEQ_ - GTOK) && !dup;
    }
    int tier = -1;
    if (valid) {
      int loc = ((i - j) <= WINDOW_) ? 1 : 0;
      int glb = (j < GTOK || j >= SEQ_ - GTOK) ? 1 : 0;
      int rnd = 0;
      for (int r = 0; r < RTOK; r++) rnd |= (rl2[h][r] == j) ? 1 : 0;
      tier = loc + glb + rnd;
      atomicMax(&stm2[h], tier);
    }
    __syncthreads();
    const int tm = stm2[h];
    if (valid && tier == tm) {
      if (iswin) {
        int pos = atomicAdd(&scw2[h], 1);
        cols[i * 128 + pos] = j;
      } else {
        int pos = 127 - atomicAdd(&scnw2[h], 1);
        cols[i * 128 + pos] = j;
      }
    }
    __syncthreads();
    if (c == 0) {
      cnt[i] = scw2[h] + scnw2[h];
      tmx[i] = tm;
      cnts2[i] = scw2[h] | (scnw2[h] << 16);
      if (i < 68 || i >= SEQ_ - 4) {
        int cc = (i < 68) ? i : 68 + (i - (SEQ_ - 4));
        qlist[cc * 2 + 0] = (tm == 3) ? i : -1;
        qlist[cc * 2 + 1] = (tm == 3) ? (SEQ_ + i) : -1;
      }
    }
  }
}

// =================== K2: Wvo weight-GEMM + tier-3 q/k/v gather-GEMMs ===============
__global__ __launch_bounds__(256) void k2_wgemm(
    const unsigned short* __restrict__ woT, const unsigned short* __restrict__ Wvs,
    unsigned short* __restrict__ WvoT, const unsigned short* __restrict__ xn,
    const unsigned short* __restrict__ wqT, const int* __restrict__ qlist,
    unsigned short* __restrict__ qf, unsigned short* __restrict__ kf,
    unsigned short* __restrict__ vf) {
  __shared__ __align__(16) unsigned short smem[2 * 12288];   // 48 KB dbuf
  const int bx = blockIdx.x, t = threadIdx.x;
  const int wave = t >> 6, lane = t & 63;
  const int quad = lane >> 4, l16 = lane & 15;
  const int wm = (wave >> 1) * 64, wn = (wave & 1) * 32;
  const int r8 = lane >> 3;
  const int swo = ((lane & 7) ^ r8) * 8;     // inverse-swizzled source chunk
  floatx4 acc[4][2] = {};
  if (bx < 128) {
    const int bm = (bx >> 4) * 128, bn = (bx & 15) * 64;
    const unsigned short* a0 = woT + (size_t)(bm + wave * 32 + r8) * DMODEL + swo;
    const unsigned short* b0 = Wvs + (size_t)(bn + wave * 16 + r8) * DMODEL + swo;
    gemm_bk64_128x64(a0, a0 + 8 * DMODEL, a0 + 16 * DMODEL, a0 + 24 * DMODEL,
                     b0, b0 + 8 * DMODEL, smem, wave, lane, acc);
    #pragma unroll
    for (int sm = 0; sm < 4; sm++)
      #pragma unroll
      for (int sn = 0; sn < 2; sn++)
        #pragma unroll
        for (int r = 0; r < 4; r++) {
          int row = bm + wm + sm * 16 + quad * 4 + r;
          int col = bn + wn + sn * 16 + l16;
          WvoT[(size_t)row * DMODEL + col] = f2bf(acc[sm][sn][r]);
        }
  } else {
    const int idx = bx - 128;
    const int job = idx >> 4, bn = (idx & 15) * 64;
    const int wsel = (job < 2) ? 0 : ((job == 2) ? 1 : 2);
    const unsigned short* BT = wqT + (size_t)wsel * DMODEL * DMODEL;
    unsigned short* dstbuf = (job == 0) ? qf
                           : (job == 1) ? (qf + (size_t)128 * DMODEL)
                           : (job == 2) ? kf : vf;
    const unsigned short* aPg[4];
    #pragma unroll
    for (int g = 0; g < 4; g++) {
      int m = wave * 32 + g * 8 + r8;        // 0..127 within tile (per-lane row)
      int row;
      if (job < 2) {
        int s = job * 128 + m;
        int ql = (s < 144) ? qlist[s] : -1;
        row = (ql < 0) ? 0 : ql;
      } else {
        row = (m < 16) ? ((m >> 3) * SEQ_ + (((m & 7) < 4) ? (m & 7) : (SEQ_ - 8 + (m & 7)))) : 0;
      }
      aPg[g] = xn + (size_t)row * DMODEL + swo;
    }
    const unsigned short* b0 = BT + (size_t)(bn + wave * 16 + r8) * DMODEL + swo;
    gemm_bk64_128x64(aPg[0], aPg[1], aPg[2], aPg[3],
                     b0, b0 + 8 * DMODEL, smem, wave, lane, acc);
    #pragma unroll
    for (int sm = 0; sm < 4; sm++)
      #pragma unroll
      for (int sn = 0; sn < 2; sn++)
        #pragma unroll
        for (int r = 0; r < 4; r++) {
          int m = wm + sm * 16 + quad * 4 + r;
          int col = bn + wn + sn * 16 + l16;
          dstbuf[(size_t)m * DMODEL + col] = f2bf(acc[sm][sn][r]);
        }
  }
}

// =================== K3: tier-3 softmax (first) + sliding-window xbar ==============
__global__ __launch_bounds__(256) void k3_xbar(
    const unsigned short* __restrict__ xn, const int* __restrict__ cols,
    const int* __restrict__ cnt, const int* __restrict__ tmx,
    const int* __restrict__ cnts2, const int* __restrict__ qlist,
    const unsigned short* __restrict__ qf, const unsigned short* __restrict__ kf,
    const unsigned short* __restrict__ vf,
    unsigned short* __restrict__ xbar, unsigned short* __restrict__ vbar) {
  const int bx = blockIdx.x, t = threadIdx.x;
  const int wave = t >> 6, lane = t & 63;
  if (bx >= 36) {
    __shared__ unsigned short win[80][256];   // rows [i0-64, i0+15] x 256 dims
    const int xb = bx - 36;
    const int b = xb >> 9, rest = xb & 511;
    const int i0 = (rest >> 2) * 16, dimbase = (rest & 3) * 256;
    const size_t xnb = (size_t)(b * SEQ_) * DMODEL;
    const int lo = i0 - 64;
    const int r0 = i0 + wave * 4;
    // ---- preload metadata for this wave's 4 rows (coalesced, before chains) ----
    int tm_[4], cw_[4], cnw_[4], jr0_[4], jr1_[4];
    #pragma unroll
    for (int rr = 0; rr < 4; rr++) {
      const int i = r0 + rr;
      tm_[rr] = tmx[i];
      int c2 = cnts2[i];
      cw_[rr] = c2 & 0xffff; cnw_[rr] = c2 >> 16;
      jr0_[rr] = cols[i * 128 + lane];
      jr1_[rr] = cols[i * 128 + 64 + lane];
    }
    // ---- stage 80 window rows, int4/lane: 2 rows per wave-iter ----
    {
      const int l5 = lane & 31, rsub = lane >> 5;
      #pragma unroll 5
      for (int it = 0; it < 10; it++) {
        int r = it * 8 + wave * 2 + rsub;
        int gr = lo + r;
        if (gr >= 0)
          *(int4*)&win[r][l5 * 8] =
              *(const int4*)(xn + xnb + (size_t)gr * DMODEL + dimbase + l5 * 8);
      }
    }
    __syncthreads();
    const unsigned short* xnd = xn + xnb + dimbase + lane * 4;
    auto add4 = [](float4& s, ushort4 v) {
      s.x += bf2f(v.x); s.y += bf2f(v.y); s.z += bf2f(v.z); s.w += bf2f(v.w);
    };
    auto sub4 = [](float4& s, ushort4 v) {
      s.x -= bf2f(v.x); s.y -= bf2f(v.y); s.z -= bf2f(v.z); s.w -= bf2f(v.w);
    };
    // ---- init sliding window sum for row r0: rows [max(0,r0-64), r0] ----
    float4 ws = {0, 0, 0, 0};
    {
      float4 t1 = {0,0,0,0}, t2 = {0,0,0,0}, t3 = {0,0,0,0};
      const int jstart = (r0 - 64 > 0) ? (r0 - 64) : 0;
      const int cn = r0 - jstart + 1;
      const int base = jstart - lo;
      int c = 0;
      for (; c + 4 <= cn; c += 4) {
        ushort4 v0 = *(const ushort4*)&win[base + c][lane * 4];
        ushort4 v1 = *(const ushort4*)&win[base + c + 1][lane * 4];
        ushort4 v2 = *(const ushort4*)&win[base + c + 2][lane * 4];
        ushort4 v3 = *(const ushort4*)&win[base + c + 3][lane * 4];
        add4(ws, v0); add4(t1, v1); add4(t2, v2); add4(t3, v3);
      }
      for (; c < cn; c++) add4(ws, *(const ushort4*)&win[base + c][lane * 4]);
      ws.x += t1.x + t2.x + t3.x; ws.y += t1.y + t2.y + t3.y;
      ws.z += t1.z + t2.z + t3.z; ws.w += t1.w + t2.w + t3.w;
    }
    for (int rr = 0; rr < 4; rr++) {
      const int i = r0 + rr;
      if (rr > 0) {   // slide: add row i, drop row i-65
        add4(ws, *(const ushort4*)&win[i - lo][lane * 4]);
        int dj = i - 65;
        if (dj >= 0) sub4(ws, *(const ushort4*)&win[dj - lo][lane * 4]);
      }
      const int tm = tm_[rr];
      ushort4 o;
      if (tm == 3) {
        o.x = o.y = o.z = o.w = 0;
      } else {
        const int cw = cw_[rr], cnw = cnw_[rr];
        const int jr1 = jr1_[rr];
        float4 s;
        if (tm == 1) {
          // s = ws + gather of cnw non-window cols; branchless global, 8-deep ILP
          s = ws;
          float4 t1 = {0,0,0,0}, t2 = {0,0,0,0}, t3 = {0,0,0,0};
          const int bb = 64 - cnw;
          int c = 0;
          for (; c + 8 <= cnw; c += 8) {
            ushort4 v0 = *(const ushort4*)(xnd + (size_t)__shfl(jr1, bb + c)     * DMODEL);
            ushort4 v1 = *(const ushort4*)(xnd + (size_t)__shfl(jr1, bb + c + 1) * DMODEL);
            ushort4 v2 = *(const ushort4*)(xnd + (size_t)__shfl(jr1, bb + c + 2) * DMODEL);
            ushort4 v3 = *(const ushort4*)(xnd + (size_t)__shfl(jr1, bb + c + 3) * DMODEL);
            ushort4 v4 = *(const ushort4*)(xnd + (size_t)__shfl(jr1, bb + c + 4) * DMODEL);
            ushort4 v5 = *(const ushort4*)(xnd + (size_t)__shfl(jr1, bb + c + 5) * DMODEL);
            ushort4 v6 = *(const ushort4*)(xnd + (size_t)__shfl(jr1, bb + c + 6) * DMODEL);
            ushort4 v7 = *(const ushort4*)(xnd + (size_t)__shfl(jr1, bb + c + 7) * DMODEL);
            add4(s, v0); add4(t1, v1); add4(t2, v2); add4(t3, v3);
            add4(s, v4); add4(t1, v5); add4(t2, v6); add4(t3, v7);
          }
          if (c + 4 <= cnw) {
            ushort4 v0 = *(const ushort4*)(xnd + (size_t)__shfl(jr1, bb + c)     * DMODEL);
            ushort4 v1 = *(const ushort4*)(xnd + (size_t)__shfl(jr1, bb + c + 1) * DMODEL);
            ushort4 v2 = *(const ushort4*)(xnd + (size_t)__shfl(jr1, bb + c + 2) * DMODEL);
            ushort4 v3 = *(const ushort4*)(xnd + (size_t)__shfl(jr1, bb + c + 3) * DMODEL);
            add4(s, v0); add4(t1, v1); add4(t2, v2); add4(t3, v3);
            c += 4;
          }
          for (; c < cnw; c++)
            add4(s, *(const ushort4*)(xnd + (size_t)__shfl(jr1, bb + c) * DMODEL));
          s.x += t1.x + t2.x + t3.x; s.y += t1.y + t2.y + t3.y;
          s.z += t1.z + t2.z + t3.z; s.w += t1.w + t2.w + t3.w;
        } else {      // tm == 2: small n, branchless global gathers
          const int jr0 = jr0_[rr];
          s.x = s.y = s.z = s.w = 0.f;
          for (int c = 0; c < cw; c++) {
            int j = (c < 64) ? __shfl(jr0, c) : __shfl(jr1, c - 64);
            add4(s, *(const ushort4*)(xnd + (size_t)j * DMODEL));
          }
          const int bb = 64 - cnw;
          for (int c = 0; c < cnw; c++)
            add4(s, *(const ushort4*)(xnd + (size_t)__shfl(jr1, bb + c) * DMODEL));
        }
        const float inv = 1.0f / (float)(cw + cnw);
        o.x = f2bf(s.x * inv); o.y = f2bf(s.y * inv);
        o.z = f2bf(s.z * inv); o.w = f2bf(s.w * inv);
      }
      *(ushort4*)(xbar + (size_t)(b * SEQ_ + i) * DMODEL + dimbase + lane * 4) = o;
    }
  } else {
    const int s = bx * 4 + wave;                // slot in [0,144)
    const int dst = (s < 144) ? qlist[s] : -1;
    if (dst < 0) return;
    const int b = dst >> 11, i = dst & (SEQ_ - 1);
    const int n = cnt[i];                       // tier-3 cols all in lower segment
    int myk = 0;
    if (lane < n) {
      int kj = cols[i * 128 + lane];
      myk = b * 8 + ((kj < 4) ? kj : (kj - (SEQ_ - 8)));
    }
    for (int h = 0; h < NHEADS; h++) {
      float qd = bf2f(qf[(size_t)s * DMODEL + h * HDIM + lane]);
      float w[8];
      float m = -1e30f;
      for (int c = 0; c < n; c++) {
        int ks = __shfl(myk, c);
        float kd = bf2f(kf[(size_t)ks * DMODEL + h * HDIM + lane]);
        float p = qd * kd;
        #pragma unroll
        for (int o = 32; o > 0; o >>= 1) p += __shfl_xor(p, o);
        p *= 0.375f;                    // 3 * (q.k / 8)
        w[c] = p;
        m = fmaxf(m, p);
      }
      float denom = 0.f, acc = 0.f;
      for (int c = 0; c < n; c++) {
        int ks = __shfl(myk, c);
        float e = __expf(w[c] - m);
        denom += e;
        acc += e * bf2f(vf[(size_t)ks * DMODEL + h * HDIM + lane]);
      }
      vbar[(size_t)s * DMODEL + h * HDIM + lane] = f2bf(acc / denom);
    }
  }
}

// =================== K4: main fused GEMM (64x64, 3-deep pipe) + fixup GEMM =========
__global__ __launch_bounds__(256) void k4_final(
    const unsigned short* __restrict__ xbar, const unsigned short* __restrict__ WvoT,
    const unsigned short* __restrict__ vbar, const unsigned short* __restrict__ woT,
    const int* __restrict__ qlist, const int* __restrict__ tmx,
    const float* __restrict__ x, float* __restrict__ out) {
  __shared__ __align__(16) unsigned short smem[3 * 8192];   // 48 KB, 3 buffers
  __shared__ int rowinf[64];
  const int bx = blockIdx.x, t = threadIdx.x;
  const int wave = t >> 6, lane = t & 63;
  const int quad = lane >> 4, l16 = lane & 15;
  const int wm = (wave >> 1) * 32, wn = (wave & 1) * 32;
  const int r8 = lane >> 3;
  const int swo = ((lane & 7) ^ r8) * 8;
  floatx4 acc[2][2] = {};
  if (bx < 1024) {
    // bijective XCD swizzle (1024 % 8 == 0): each XCD owns 8 contiguous A
    // row-panels (1 MB) + WvoT (2 MB) -> redundant panel reads are L2-hits (T1)
    const int bs = (bx & 7) * 128 + (bx >> 3);
    const int bm = (bs >> 4) * 64, bn = (bs & 15) * 64;
    if (t < 64) rowinf[t] = tmx[(bm + t) & (SEQ_ - 1)];
    const unsigned short* a0 = xbar + (size_t)(bm + wave * 16 + r8) * DMODEL + swo;
    const unsigned short* b0 = WvoT + (size_t)(bn + wave * 16 + r8) * DMODEL + swo;
    gemm_bk64_64x64_p3(a0, a0 + 8 * DMODEL, b0, b0 + 8 * DMODEL, smem, wave, lane, acc);
    #pragma unroll
    for (int sm = 0; sm < 2; sm++)
      #pragma unroll
      for (int sn = 0; sn < 2; sn++)
        #pragma unroll
        for (int r = 0; r < 4; r++) {
          int m = wm + sm * 16 + quad * 4 + r;
          if (rowinf[m] != 3) {
            int col = bn + wn + sn * 16 + l16;
            size_t off = (size_t)(bm + m) * DMODEL + col;
            out[off] = acc[sm][sn][r] + x[off];
          }
        }
  } else {
    const int idx = bx - 1024;                   // [0,48): 3 row-blocks x 16 cols
    const int bm = (idx >> 4) * 64, bn = (idx & 15) * 64;
    if (t < 64) {
      int s = bm + t;
      rowinf[t] = (s < 144) ? qlist[s] : -1;
    }
    const unsigned short* a0 = vbar + (size_t)(bm + wave * 16 + r8) * DMODEL + swo;
    const unsigned short* b0 = woT + (size_t)(bn + wave * 16 + r8) * DMODEL + swo;
    gemm_bk64_64x64_p3(a0, a0 + 8 * DMODEL, b0, b0 + 8 * DMODEL, smem, wave, lane, acc);
    #pragma unroll
    for (int sm = 0; sm < 2; sm++)
      #pragma unroll
      for (int sn = 0; sn < 2; sn++)
        #pragma unroll
        for (int r = 0; r < 4; r++) {
          int m = wm + sm * 16 + quad * 4 + r;
          int dst = rowinf[m];
          if (dst >= 0) {
            int col = bn + wn + sn * 16 + l16;
            size_t off = (size_t)dst * DMODEL + col;
            out[off] = acc[sm][sn][r] + x[off];
          }
        }
  }
}

extern "C" void kernel_launch(void* const* d_in, const int* in_sizes, int n_in,
                              void* d_out, int out_size, void* d_ws, size_t ws_size,
                              hipStream_t stream) {
  const float* x     = (const float*)d_in[0];
  const float* w_qkv = (const float*)d_in[1];
  const float* w_out = (const float*)d_in[2];
  const float* gamma = (const float*)d_in[3];
  const float* beta  = (const float*)d_in[4];
  const int*   ridx  = (const int*)d_in[5];
  float* out = (float*)d_out;

  char* ws = (char*)d_ws;
  size_t off = 0;
  auto alloc = [&](size_t bytes) {
    char* p = ws + off;
    off = (off + bytes + 255) & ~(size_t)255;
    return p;
  };
  unsigned short* xn   = (unsigned short*)alloc((size_t)ROWS * DMODEL * 2);     // 8 MB
  unsigned short* wqT  = (unsigned short*)alloc((size_t)QKVN * DMODEL * 2);     // 6 MB
  unsigned short* woT  = (unsigned short*)alloc((size_t)DMODEL * DMODEL * 2);   // 2 MB
  unsigned short* Wvs  = (unsigned short*)alloc((size_t)DMODEL * DMODEL * 2);   // 2 MB
  unsigned short* WvoT = (unsigned short*)alloc((size_t)DMODEL * DMODEL * 2);   // 2 MB
  unsigned short* xbar = (unsigned short*)alloc((size_t)ROWS * DMODEL * 2);     // 8 MB
  unsigned short* qf   = (unsigned short*)alloc((size_t)256 * DMODEL * 2);
  unsigned short* kf   = (unsigned short*)alloc((size_t)128 * DMODEL * 2);
  unsigned short* vf   = (unsigned short*)alloc((size_t)128 * DMODEL * 2);
  unsigned short* vbar = (unsigned short*)alloc((size_t)256 * DMODEL * 2);
  int* cols  = (int*)alloc((size_t)SEQ_ * 128 * 4);                             // 1 MB
  int* cnt   = (int*)alloc((size_t)SEQ_ * 4);
  int* tmx   = (int*)alloc((size_t)SEQ_ * 4);
  int* cnts2 = (int*)alloc((size_t)SEQ_ * 4);
  int* qlist = (int*)alloc(256 * 4);

  hipLaunchKernelGGL(k1_prep, dim3(4608), dim3(256), 0, stream,
                     x, w_qkv, w_out, gamma, beta, ridx,
                     xn, wqT, woT, Wvs, cols, cnt, tmx, cnts2, qlist);
  hipLaunchKernelGGL(k2_wgemm, dim3(192), dim3(256), 0, stream,
                     woT, Wvs, WvoT, xn, wqT, qlist, qf, kf, vf);
  hipLaunchKernelGGL(k3_xbar, dim3(1060), dim3(256), 0, stream,
                     xn, cols, cnt, tmx, cnts2, qlist, qf, kf, vf, xbar, vbar);
  hipLaunchKernelGGL(k4_final, dim3(1072), dim3(256), 0, stream,
                     xbar, WvoT, vbar, woT, qlist, tmx, x, out);
}